// Round 9
// baseline (535.346 us; speedup 1.0000x reference)
//
#include <hip/hip_runtime.h>
#include <math.h>

#define NN 50000
#define NE 800000
#define NG 64
#define D 128
#define IMG 4096
#define NT 30
#define SCAN_BLOCKS ((NN + 255) / 256)

typedef unsigned int uint;
typedef unsigned short ushort;
typedef __attribute__((ext_vector_type(8))) __bf16 bf16x8;
typedef __attribute__((ext_vector_type(4))) float f32x4;

__device__ __forceinline__ uint bf16rne(float f) {
  uint h = __float_as_uint(f);
  return (h + 0x7fffu + ((h >> 16) & 1u)) >> 16;
}
__device__ __forceinline__ uint pack2bf(float a, float b) {
  return bf16rne(a) | (bf16rne(b) << 16);
}
__device__ __forceinline__ float bflo(uint u) { return __uint_as_float(u << 16); }
__device__ __forceinline__ float bfhi(uint u) { return __uint_as_float(u & 0xffff0000u); }

// X / xw bf16 storage: ROW-MAJOR, 64 uints (128 bf16) per node row.

// ---------------- graph preprocessing ----------------

__global__ void edge_slot(const int* __restrict__ col, int* __restrict__ cnt,
                          int* __restrict__ slot) {
  int e = blockIdx.x * 256 + threadIdx.x;
  if (e < NE) {
    int c = col[e];
    slot[e] = atomicAdd(&cnt[c], 1);
  }
}

__global__ __launch_bounds__(256) void scan_blocks(const int* __restrict__ cnt,
                                                   int* __restrict__ incl,
                                                   int* __restrict__ partial) {
  __shared__ int sd[256];
  int t = threadIdx.x;
  int i = blockIdx.x * 256 + t;
  int v = (i < NN) ? cnt[i] : 0;
  sd[t] = v;
  __syncthreads();
  #pragma unroll
  for (int s = 1; s < 256; s <<= 1) {
    int add = (t >= s) ? sd[t - s] : 0;
    __syncthreads();
    sd[t] += add;
    __syncthreads();
  }
  if (i < NN) incl[i] = sd[t];
  if (t == 255) partial[blockIdx.x] = sd[255];
}

__global__ __launch_bounds__(256) void scan_partials(int* __restrict__ partial, int nb) {
  __shared__ int sd[256];
  int t = threadIdx.x;
  int v = (t < nb) ? partial[t] : 0;
  sd[t] = v;
  __syncthreads();
  #pragma unroll
  for (int s = 1; s < 256; s <<= 1) {
    int add = (t >= s) ? sd[t - s] : 0;
    __syncthreads();
    sd[t] += add;
    __syncthreads();
  }
  if (t < nb) partial[t] = (t == 0) ? 0 : sd[t - 1];
}

__global__ __launch_bounds__(256) void scan_apply(const int* __restrict__ incl,
                                                  const int* __restrict__ partial,
                                                  int* __restrict__ off) {
  int i = blockIdx.x * 256 + threadIdx.x;
  if (i < NN) off[i + 1] = incl[i] + partial[blockIdx.x];
  if (i == 0) off[0] = 0;
}

__global__ void fill_scatter(const int* __restrict__ row, const int* __restrict__ col,
                             const float* __restrict__ ew, const int* __restrict__ off,
                             const int* __restrict__ slot, int* __restrict__ src_s,
                             float* __restrict__ ew_s) {
  int e = blockIdx.x * 256 + threadIdx.x;
  if (e < NE) {
    int idx = off[col[e]] + slot[e];
    src_s[idx] = row[e];
    ew_s[idx] = ew[e];
  }
}

// 16 lanes per node: coalesced CSR segment reads, shfl reduce
__global__ __launch_bounds__(256) void deg_csr(const int* __restrict__ off,
                                               const float* __restrict__ ew_s,
                                               float* __restrict__ dis) {
  int lane = threadIdx.x & 63;
  int sub = lane >> 4, fl = lane & 15;
  int node = (blockIdx.x * 4 + (threadIdx.x >> 6)) * 4 + sub;
  if (node >= NN) return;
  int s = off[node], e = off[node + 1];
  float acc = 0.f;
  for (int j = s + fl; j < e; j += 16) acc += ew_s[j];
  acc += __shfl_xor(acc, 8);
  acc += __shfl_xor(acc, 4);
  acc += __shfl_xor(acc, 2);
  acc += __shfl_xor(acc, 1);
  if (fl == 0) dis[node] = 1.0f / sqrtf(acc + 1.0f);
}

// 16 lanes per node: norm_s[j] = dis[src]*ew*dis[node]; styp_s[j] = type[src]
__global__ __launch_bounds__(256) void norm_fill(const int* __restrict__ off,
                                                 const int* __restrict__ src_s,
                                                 const float* __restrict__ ew_s,
                                                 const float* __restrict__ dis,
                                                 const int* __restrict__ types,
                                                 float* __restrict__ norm_s,
                                                 int* __restrict__ styp_s) {
  int lane = threadIdx.x & 63;
  int sub = lane >> 4, fl = lane & 15;
  int node = (blockIdx.x * 4 + (threadIdx.x >> 6)) * 4 + sub;
  if (node >= NN) return;
  int s = off[node], e = off[node + 1];
  float dc = dis[node];
  for (int j = s + fl; j < e; j += 16) {
    int sv = src_s[j];
    norm_s[j] = dis[sv] * ew_s[j] * dc;
    styp_s[j] = types[sv];
  }
}

// embW[t][n] = sum_k emb[t][k] * W1[n][k]   (30 x 128)
__global__ void embw_k(const float* __restrict__ emb, const float* __restrict__ W,
                       float* __restrict__ embW) {
  int tid = blockIdx.x * 256 + threadIdx.x;
  if (tid < NT * D) {
    int t = tid >> 7, n = tid & 127;
    const float* e = emb + (size_t)t * D;
    const float* w = W + (size_t)n * D;
    float acc = 0.f;
    for (int k = 0; k < D; k += 4) {
      float4 ev = *(const float4*)(e + k);
      float4 wv = *(const float4*)(w + k);
      acc += ev.x * wv.x + ev.y * wv.y + ev.z * wv.z + ev.w * wv.w;
    }
    embW[tid] = acc;
  }
}

__global__ void convW(const float* __restrict__ W, uint* __restrict__ Wbf) {
  int idx = blockIdx.x * 256 + threadIdx.x;  // 128*64
  if (idx < D * 64) {
    float2 v = ((const float2*)W)[idx];
    Wbf[idx] = pack2bf(v.x, v.y);
  }
}

// ---------------- layer 1 fused: X1 = relu(C @ embW1 + b1), bf16 row-major out ----------------

__global__ __launch_bounds__(256) void lay1_fused(const int* __restrict__ off,
                                                  const int* __restrict__ styp_s,
                                                  const float* __restrict__ norm_s,
                                                  const float* __restrict__ dis,
                                                  const int* __restrict__ types,
                                                  const float* __restrict__ embW,
                                                  const float* __restrict__ b1,
                                                  uint* __restrict__ outbf) {
  __shared__ float sE[NT * D];
  __shared__ float sC[16][32];
  __shared__ float sB[D];
  int t = threadIdx.x;
  for (int i = t; i < NT * D; i += 256) sE[i] = embW[i];
  if (t < D) sB[t] = b1[t];
  for (int i = t; i < 16 * 32; i += 256) ((float*)sC)[i] = 0.f;
  __syncthreads();
  int wave = t >> 6, lane = t & 63;
  int nodebase = blockIdx.x * 16;
  #pragma unroll
  for (int r = 0; r < 4; r++) {
    int li = wave * 4 + r;
    int node = nodebase + li;
    if (node < NN) {
      int s = off[node], e = off[node + 1];
      for (int idx = s + lane; idx < e; idx += 64)
        atomicAdd(&sC[li][styp_s[idx]], norm_s[idx]);
      if (lane == 0) {
        float dd = dis[node];
        atomicAdd(&sC[li][types[node]], dd * dd);
      }
    }
  }
  __syncthreads();
  #pragma unroll
  for (int r = 0; r < 4; r++) {
    int li = wave * 4 + r;
    int node = nodebase + li;
    if (node < NN) {
      float2 acc = *(const float2*)&sB[lane * 2];
      #pragma unroll
      for (int tt = 0; tt < NT; tt++) {
        float c = sC[li][tt];
        float2 ev = *(const float2*)&sE[tt * D + lane * 2];
        acc.x = fmaf(c, ev.x, acc.x);
        acc.y = fmaf(c, ev.y, acc.y);
      }
      acc.x = fmaxf(acc.x, 0.f);
      acc.y = fmaxf(acc.y, 0.f);
      outbf[(size_t)node * 64 + lane] = pack2bf(acc.x, acc.y);
    }
  }
}

// ---------------- node GEMM via MFMA: xw = X @ W^T (bf16 row-major in/out) ----------------

__global__ __launch_bounds__(256) void node_gemm_mfma(const uint* __restrict__ Abf,
                                                      const uint* __restrict__ Wbf,
                                                      uint* __restrict__ outbf) {
  __shared__ ushort tile[4][16][136];
  int w = threadIdx.x >> 6, lane = threadIdx.x & 63;
  int quad = lane >> 4;
  int m0 = blockIdx.x * 64 + w * 16;
  int mrow = m0 + (lane & 15);
  int arow = (mrow < NN) ? mrow : 0;
  uint4 afr[4];
  #pragma unroll
  for (int ks = 0; ks < 4; ks++)
    afr[ks] = *(const uint4*)(Abf + (size_t)arow * 64 + ks * 16 + quad * 4);
  f32x4 acc[8] = {};
  #pragma unroll
  for (int nt = 0; nt < 8; nt++) {
    int n = nt * 16 + (lane & 15);
    #pragma unroll
    for (int ks = 0; ks < 4; ks++) {
      union { uint4 u; bf16x8 v; } au, bu;
      au.u = afr[ks];
      bu.u = *(const uint4*)(Wbf + (size_t)n * 64 + ks * 16 + quad * 4);
      acc[nt] = __builtin_amdgcn_mfma_f32_16x16x32_bf16(au.v, bu.v, acc[nt], 0, 0, 0);
    }
  }
  #pragma unroll
  for (int nt = 0; nt < 8; nt++)
    #pragma unroll
    for (int i = 0; i < 4; i++)
      tile[w][quad * 4 + i][nt * 16 + (lane & 15)] = (ushort)bf16rne(acc[nt][i]);
  __builtin_amdgcn_s_waitcnt(0);  // wave-local LDS ordering (per-wave tile)
  #pragma unroll
  for (int rep = 0; rep < 4; rep++) {
    int r = rep * 4 + quad;
    int j = lane & 15;
    int node = m0 + r;
    if (node < NN) {
      uint4 v = *(const uint4*)&tile[w][r][j * 8];
      *(uint4*)(outbf + (size_t)node * 64 + j * 4) = v;
    }
  }
}

// ---------------- CSR aggregation: one wave per node, bf16 gather, 16x MLP ----------------

__global__ __launch_bounds__(256) void aggregate(const uint* __restrict__ xw,
                                                 const int* __restrict__ off,
                                                 const int* __restrict__ src_s,
                                                 const float* __restrict__ norm_s,
                                                 const float* __restrict__ dis,
                                                 const float* __restrict__ bias, int relu,
                                                 uint* __restrict__ outbf,
                                                 float* __restrict__ outf) {
  int wave = threadIdx.x >> 6;
  int lane = threadIdx.x & 63;
  int node = blockIdx.x * 4 + wave;
  if (node >= NN) return;
  float accx = 0.f, accy = 0.f;
  int s = off[node], e = off[node + 1];
  int idx = s;
  int astart = (s + 3) & ~3;
  if (astart > e) astart = e;
  for (; idx < astart; idx++) {
    int src = src_s[idx];
    float nm = norm_s[idx];
    uint u = xw[(size_t)src * 64 + lane];
    accx = fmaf(nm, bflo(u), accx);
    accy = fmaf(nm, bfhi(u), accy);
  }
  // 16 gathers in flight
  for (; idx + 16 <= e; idx += 16) {
    int4 sa[4];
    float4 na[4];
    #pragma unroll
    for (int q = 0; q < 4; q++) {
      sa[q] = *(const int4*)(src_s + idx + q * 4);
      na[q] = *(const float4*)(norm_s + idx + q * 4);
    }
    uint u[16];
    #pragma unroll
    for (int q = 0; q < 4; q++) {
      u[q * 4 + 0] = xw[(size_t)sa[q].x * 64 + lane];
      u[q * 4 + 1] = xw[(size_t)sa[q].y * 64 + lane];
      u[q * 4 + 2] = xw[(size_t)sa[q].z * 64 + lane];
      u[q * 4 + 3] = xw[(size_t)sa[q].w * 64 + lane];
    }
    #pragma unroll
    for (int q = 0; q < 4; q++) {
      float nm[4] = {na[q].x, na[q].y, na[q].z, na[q].w};
      #pragma unroll
      for (int r = 0; r < 4; r++) {
        accx = fmaf(nm[r], bflo(u[q * 4 + r]), accx);
        accy = fmaf(nm[r], bfhi(u[q * 4 + r]), accy);
      }
    }
  }
  for (; idx + 4 <= e; idx += 4) {
    int4 sr = *(const int4*)(src_s + idx);
    float4 nm = *(const float4*)(norm_s + idx);
    uint u0 = xw[(size_t)sr.x * 64 + lane];
    uint u1 = xw[(size_t)sr.y * 64 + lane];
    uint u2 = xw[(size_t)sr.z * 64 + lane];
    uint u3 = xw[(size_t)sr.w * 64 + lane];
    accx = fmaf(nm.x, bflo(u0), accx);
    accy = fmaf(nm.x, bfhi(u0), accy);
    accx = fmaf(nm.y, bflo(u1), accx);
    accy = fmaf(nm.y, bfhi(u1), accy);
    accx = fmaf(nm.z, bflo(u2), accx);
    accy = fmaf(nm.z, bfhi(u2), accy);
    accx = fmaf(nm.w, bflo(u3), accx);
    accy = fmaf(nm.w, bfhi(u3), accy);
  }
  for (; idx < e; idx++) {
    int src = src_s[idx];
    float nm = norm_s[idx];
    uint u = xw[(size_t)src * 64 + lane];
    accx = fmaf(nm, bflo(u), accx);
    accy = fmaf(nm, bfhi(u), accy);
  }
  float dd = dis[node];
  dd = dd * dd;
  {
    uint u = xw[(size_t)node * 64 + lane];
    accx = fmaf(dd, bflo(u), accx);
    accy = fmaf(dd, bfhi(u), accy);
  }
  float2 b = ((const float2*)bias)[lane];
  accx += b.x;
  accy += b.y;
  if (relu) {
    accx = fmaxf(accx, 0.f);
    accy = fmaxf(accy, 0.f);
  }
  if (outbf) outbf[(size_t)node * 64 + lane] = pack2bf(accx, accy);
  else ((float2*)outf)[(size_t)node * 64 + lane] = make_float2(accx, accy);
}

// ---------------- image GEMM via MFMA: xi = images @ W_img.T + b_img ----------------

__global__ void convA(const float* __restrict__ A, uint* __restrict__ Abf) {
  int idx = blockIdx.x * 256 + threadIdx.x;
  if (idx < 64 * IMG / 2) {
    float2 v = ((const float2*)A)[idx];
    Abf[idx] = pack2bf(v.x, v.y);
  }
}

__global__ __launch_bounds__(256) void img_mfma(const uint* __restrict__ Abf,
                                                const float* __restrict__ W,
                                                float* __restrict__ splitbuf) {
  int wv = threadIdx.x >> 6, lane = threadIdx.x & 63;
  int n = blockIdx.x * 64 + wv * 16 + (lane & 15);
  int kq = (lane >> 4) * 8;
  int k0 = blockIdx.y * 512 + kq;
  f32x4 acc[4] = {{0.f, 0.f, 0.f, 0.f}, {0.f, 0.f, 0.f, 0.f},
                  {0.f, 0.f, 0.f, 0.f}, {0.f, 0.f, 0.f, 0.f}};
  const float* wp = W + (size_t)n * IMG + k0;
  const uint* ap = Abf + (size_t)(lane & 15) * (IMG / 2) + k0 / 2;
  for (int ks = 0; ks < 512; ks += 32) {
    float4 w0 = *(const float4*)(wp + ks);
    float4 w1 = *(const float4*)(wp + ks + 4);
    union { uint4 u; bf16x8 v; } bu;
    bu.u.x = pack2bf(w0.x, w0.y);
    bu.u.y = pack2bf(w0.z, w0.w);
    bu.u.z = pack2bf(w1.x, w1.y);
    bu.u.w = pack2bf(w1.z, w1.w);
    #pragma unroll
    for (int mt = 0; mt < 4; mt++) {
      union { uint4 u; bf16x8 v; } au;
      au.u = *(const uint4*)(ap + (size_t)mt * 16 * (IMG / 2) + ks / 2);
      acc[mt] = __builtin_amdgcn_mfma_f32_16x16x32_bf16(au.v, bu.v, acc[mt], 0, 0, 0);
    }
  }
  #pragma unroll
  for (int mt = 0; mt < 4; mt++)
    #pragma unroll
    for (int i = 0; i < 4; i++) {
      int m = mt * 16 + (lane >> 4) * 4 + i;
      splitbuf[((size_t)blockIdx.y * 64 + m) * IMG + n] = acc[mt][i];
    }
}

__global__ __launch_bounds__(256) void img_reduce(const float* __restrict__ splitbuf,
                                                  const float* __restrict__ bias,
                                                  float* __restrict__ xi) {
  int idx = blockIdx.x * 256 + threadIdx.x;
  if (idx < 64 * IMG) {
    float acc = bias[idx & (IMG - 1)];
    #pragma unroll
    for (int s = 0; s < 8; s++) acc += splitbuf[(size_t)s * 64 * IMG + idx];
    xi[idx] = acc;
  }
}

// ---------------- head GEMM via MFMA: out[64][128] = A[64][K] @ W[128][K]^T ----------------
// Split-k partials; A and W fp32, converted in-register. Block = 4 waves (one m-tile each).

__global__ __launch_bounds__(256) void head_mfma(const float* __restrict__ A,
                                                 const float* __restrict__ W,
                                                 float* __restrict__ part, int K,
                                                 int kChunk) {
  int w = threadIdx.x >> 6, lane = threadIdx.x & 63;
  int quad = lane >> 4;
  int m = w * 16 + (lane & 15);  // A-frag row
  int k0 = blockIdx.x * kChunk;
  int kEnd = min(K, k0 + kChunk);
  f32x4 acc[8] = {};
  for (int k = k0; k < kEnd; k += 32) {
    const float* ap = A + (size_t)m * K + k + quad * 8;
    union { uint4 u; bf16x8 v; } au;
    au.u.x = pack2bf(ap[0], ap[1]);
    au.u.y = pack2bf(ap[2], ap[3]);
    au.u.z = pack2bf(ap[4], ap[5]);
    au.u.w = pack2bf(ap[6], ap[7]);
    #pragma unroll
    for (int nt = 0; nt < 8; nt++) {
      int n = nt * 16 + (lane & 15);
      const float* wp = W + (size_t)n * K + k + quad * 8;
      union { uint4 u; bf16x8 v; } bu;
      bu.u.x = pack2bf(wp[0], wp[1]);
      bu.u.y = pack2bf(wp[2], wp[3]);
      bu.u.z = pack2bf(wp[4], wp[5]);
      bu.u.w = pack2bf(wp[6], wp[7]);
      acc[nt] = __builtin_amdgcn_mfma_f32_16x16x32_bf16(au.v, bu.v, acc[nt], 0, 0, 0);
    }
  }
  #pragma unroll
  for (int nt = 0; nt < 8; nt++)
    #pragma unroll
    for (int i = 0; i < 4; i++) {
      int mo = w * 16 + quad * 4 + i;
      int n = nt * 16 + (lane & 15);
      part[(size_t)blockIdx.x * 64 * 128 + (size_t)mo * 128 + n] = acc[nt][i];
    }
}

__global__ __launch_bounds__(256) void head_reduce(const float* __restrict__ part,
                                                   const float* __restrict__ bias,
                                                   float* __restrict__ out, int nch) {
  int idx = blockIdx.x * 256 + threadIdx.x;
  if (idx < 64 * 128) {
    float acc = bias[idx & 127];
    for (int s = 0; s < nch; s++) acc += part[(size_t)s * 64 * 128 + idx];
    out[idx] = acc;
  }
}

// ---------------- pooling + epilogue ----------------

__global__ void graph_bounds(const int* __restrict__ batch, int* __restrict__ goff) {
  int g = threadIdx.x;
  if (g <= NG) {
    int lo = 0, hi = NN;
    while (lo < hi) {
      int mid = (lo + hi) >> 1;
      if (batch[mid] < g) lo = mid + 1; else hi = mid;
    }
    goff[g] = lo;
  }
}

__global__ __launch_bounds__(128) void pool_partial(const float* __restrict__ xg,
                                                    const int* __restrict__ goff,
                                                    float* __restrict__ pooled) {
  int g = blockIdx.x;
  int chunk = blockIdx.y;
  int t = threadIdx.x;
  int s = goff[g], e = goff[g + 1];
  float acc = 0.f;
  for (int i = s + chunk; i < e; i += 8) acc += xg[(size_t)i * D + t];
  atomicAdd(&pooled[g * D + t], acc);
}

__global__ __launch_bounds__(128) void pool_finish(float* __restrict__ pooled,
                                                   const int* __restrict__ goff) {
  int g = blockIdx.x;
  int t = threadIdx.x;
  int c = goff[g + 1] - goff[g];
  pooled[g * D + t] /= fmaxf((float)c, 1.0f);
}

__global__ __launch_bounds__(256) void build_xcat(const float* __restrict__ xi,
                                                  const float* __restrict__ pooled,
                                                  float* __restrict__ xcat) {
  int idx = blockIdx.x * 256 + threadIdx.x;
  if (idx < 64 * 1056) {
    int r = idx / 1056;
    int c = idx % 1056;
    float4 v = (c < 1024) ? ((const float4*)xi)[r * 1024 + c]
                          : ((const float4*)pooled)[r * 32 + (c - 1024)];
    ((float4*)xcat)[idx] = v;
  }
}

__global__ __launch_bounds__(128) void normalize_rows(const float* __restrict__ oi_raw,
                                                      const float* __restrict__ oc_raw,
                                                      float* __restrict__ out) {
  int r = blockIdx.x;
  int t = threadIdx.x;
  const float* src = (r < 64) ? (oi_raw + r * D) : (oc_raw + (r - 64) * D);
  float v = src[t];
  __shared__ float red[128];
  red[t] = v * v;
  __syncthreads();
  for (int s = 64; s > 0; s >>= 1) {
    if (t < s) red[t] += red[t + s];
    __syncthreads();
  }
  out[r * D + t] = v / sqrtf(red[0]);
}

// ---------------- launch ----------------

extern "C" void kernel_launch(void* const* d_in, const int* in_sizes, int n_in,
                              void* d_out, int out_size, void* d_ws, size_t ws_size,
                              hipStream_t stream) {
  const float* images = (const float*)d_in[0];
  const int* node_types = (const int*)d_in[1];
  const int* erow = (const int*)d_in[2];
  const int* ecol = erow + NE;
  const float* eattr = (const float*)d_in[3];
  const int* batch = (const int*)d_in[4];
  const float* emb = (const float*)d_in[5];
  const float* W_img = (const float*)d_in[6];
  const float* b_img = (const float*)d_in[7];
  const float* W1 = (const float*)d_in[8];
  const float* b1 = (const float*)d_in[9];
  const float* W2 = (const float*)d_in[10];
  const float* b2 = (const float*)d_in[11];
  const float* W3 = (const float*)d_in[12];
  const float* b3 = (const float*)d_in[13];
  const float* Wi = (const float*)d_in[14];
  const float* bi = (const float*)d_in[15];
  const float* Wc = (const float*)d_in[16];
  const float* bc = (const float*)d_in[17];
  float* out = (float*)d_out;

  char* w = (char*)d_ws;
  auto alloc = [&](size_t bytes) -> void* {
    void* p = (void*)w;
    w += (bytes + 511) & ~(size_t)511;
    return p;
  };
  int* cnt_i = (int*)alloc(NN * 4);
  float* pooled = (float*)alloc(64 * D * 4);
  size_t zero_bytes = (size_t)(w - (char*)d_ws);  // cnt + pooled need zeroing
  int* csr_off = (int*)alloc((NN + 1) * 4);
  int* goff = (int*)alloc((NG + 1) * 4);
  int* scan_incl = (int*)alloc(NN * 4);
  int* scan_part = (int*)alloc(SCAN_BLOCKS * 4);
  int* slot = (int*)alloc((size_t)NE * 4);
  int* src_s = (int*)alloc((size_t)NE * 4);
  float* ew_s = (float*)alloc((size_t)NE * 4);
  float* norm_s = (float*)alloc((size_t)NE * 4);
  int* styp_s = (int*)alloc((size_t)NE * 4);
  float* dis = (float*)alloc(NN * 4);
  float* embW1 = (float*)alloc(NT * D * 4);
  uint* wbf2 = (uint*)alloc(D * 64 * 4);
  uint* wbf3 = (uint*)alloc(D * 64 * 4);
  float* bufA = (float*)alloc((size_t)NN * D * 4);    // X3 fp32 (for pooling)
  uint* bufX = (uint*)alloc((size_t)NN * D * 2);      // X bf16 rows
  uint* bufB = (uint*)alloc((size_t)NN * D * 2);      // xw bf16 rows
  float* xi = (float*)alloc((size_t)64 * IMG * 4);
  float* xcat = (float*)alloc((size_t)64 * (IMG + D) * 4);
  float* oi_raw = (float*)alloc(64 * D * 4);
  float* oc_raw = (float*)alloc(64 * D * 4);
  uint* imgAbf = (uint*)alloc((size_t)64 * IMG * 2);
  float* splitbuf = (float*)alloc((size_t)8 * 64 * IMG * 4);
  float* headI = (float*)alloc((size_t)32 * 64 * 128 * 4);
  float* headC = (float*)alloc((size_t)33 * 64 * 128 * 4);

  hipMemsetAsync(d_ws, 0, zero_bytes, stream);

  // graph preprocessing
  edge_slot<<<NE / 256, 256, 0, stream>>>(ecol, cnt_i, slot);
  scan_blocks<<<SCAN_BLOCKS, 256, 0, stream>>>(cnt_i, scan_incl, scan_part);
  scan_partials<<<1, 256, 0, stream>>>(scan_part, SCAN_BLOCKS);
  scan_apply<<<SCAN_BLOCKS, 256, 0, stream>>>(scan_incl, scan_part, csr_off);
  fill_scatter<<<NE / 256, 256, 0, stream>>>(erow, ecol, eattr, csr_off, slot, src_s, ew_s);
  deg_csr<<<(NN + 15) / 16, 256, 0, stream>>>(csr_off, ew_s, dis);
  norm_fill<<<(NN + 15) / 16, 256, 0, stream>>>(csr_off, src_s, ew_s, dis, node_types,
                                                norm_s, styp_s);

  // layer 1 collapsed: X1 = relu(C @ (emb @ W1^T) + b1) -> bf16 rows
  embw_k<<<(NT * D + 255) / 256, 256, 0, stream>>>(emb, W1, embW1);
  lay1_fused<<<(NN + 15) / 16, 256, 0, stream>>>(csr_off, styp_s, norm_s, dis, node_types,
                                                 embW1, b1, bufX);

  // layers 2 & 3: MFMA GEMM + monolithic aggregation
  convW<<<(D * 64 + 255) / 256, 256, 0, stream>>>(W2, wbf2);
  convW<<<(D * 64 + 255) / 256, 256, 0, stream>>>(W3, wbf3);
  int gblk = (NN + 63) / 64;
  node_gemm_mfma<<<gblk, 256, 0, stream>>>(bufX, wbf2, bufB);
  aggregate<<<(NN + 3) / 4, 256, 0, stream>>>(bufB, csr_off, src_s, norm_s, dis, b2, 1,
                                              bufX, (float*)0);
  node_gemm_mfma<<<gblk, 256, 0, stream>>>(bufX, wbf3, bufB);
  aggregate<<<(NN + 3) / 4, 256, 0, stream>>>(bufB, csr_off, src_s, norm_s, dis, b3, 0,
                                              (uint*)0, bufA);

  // pooling
  graph_bounds<<<1, 128, 0, stream>>>(batch, goff);
  {
    dim3 g(NG, 8);
    pool_partial<<<g, 128, 0, stream>>>(bufA, goff, pooled);
  }
  pool_finish<<<NG, 128, 0, stream>>>(pooled, goff);

  // image path: xi = images @ W_img.T + b_img  (bf16 MFMA, split-k)
  convA<<<(64 * IMG / 2 + 255) / 256, 256, 0, stream>>>(images, imgAbf);
  {
    dim3 g(IMG / 64, 8);
    img_mfma<<<g, 256, 0, stream>>>(imgAbf, W_img, splitbuf);
  }
  img_reduce<<<(64 * IMG + 255) / 256, 256, 0, stream>>>(splitbuf, b_img, xi);

  // heads via MFMA split-k
  head_mfma<<<32, 256, 0, stream>>>(xi, Wi, headI, IMG, 128);
  head_reduce<<<(64 * 128 + 255) / 256, 256, 0, stream>>>(headI, bi, oi_raw, 32);
  build_xcat<<<(64 * 1056 + 255) / 256, 256, 0, stream>>>(xi, pooled, xcat);
  head_mfma<<<33, 256, 0, stream>>>(xcat, Wc, headC, IMG + D, 128);
  head_reduce<<<(64 * 128 + 255) / 256, 256, 0, stream>>>(headC, bc, oc_raw, 33);
  normalize_rows<<<128, 128, 0, stream>>>(oi_raw, oc_raw, out);
}

// Round 10
// 478.003 us; speedup vs baseline: 1.1200x; 1.1200x over previous
//
#include <hip/hip_runtime.h>
#include <math.h>

#define NN 50000
#define NE 800000
#define NG 64
#define D 128
#define IMG 4096
#define NT 30
#define SCAN_BLOCKS ((NN + 255) / 256)

typedef unsigned int uint;
typedef unsigned short ushort;
typedef __attribute__((ext_vector_type(8))) __bf16 bf16x8;
typedef __attribute__((ext_vector_type(4))) float f32x4;

__device__ __forceinline__ uint bf16rne(float f) {
  uint h = __float_as_uint(f);
  return (h + 0x7fffu + ((h >> 16) & 1u)) >> 16;
}
__device__ __forceinline__ uint pack2bf(float a, float b) {
  return bf16rne(a) | (bf16rne(b) << 16);
}
__device__ __forceinline__ float bflo(uint u) { return __uint_as_float(u << 16); }
__device__ __forceinline__ float bfhi(uint u) { return __uint_as_float(u & 0xffff0000u); }

// X / xw bf16 storage: ROW-MAJOR, 64 uints (128 bf16) per node row.

// ---------------- graph preprocessing ----------------

__global__ void edge_slot(const int* __restrict__ col, int* __restrict__ cnt,
                          int* __restrict__ slot) {
  int e = blockIdx.x * 256 + threadIdx.x;
  if (e < NE) {
    int c = col[e];
    slot[e] = atomicAdd(&cnt[c], 1);
  }
}

__global__ __launch_bounds__(256) void scan_blocks(const int* __restrict__ cnt,
                                                   int* __restrict__ incl,
                                                   int* __restrict__ partial) {
  __shared__ int sd[256];
  int t = threadIdx.x;
  int i = blockIdx.x * 256 + t;
  int v = (i < NN) ? cnt[i] : 0;
  sd[t] = v;
  __syncthreads();
  #pragma unroll
  for (int s = 1; s < 256; s <<= 1) {
    int add = (t >= s) ? sd[t - s] : 0;
    __syncthreads();
    sd[t] += add;
    __syncthreads();
  }
  if (i < NN) incl[i] = sd[t];
  if (t == 255) partial[blockIdx.x] = sd[255];
}

__global__ __launch_bounds__(256) void scan_partials(int* __restrict__ partial, int nb) {
  __shared__ int sd[256];
  int t = threadIdx.x;
  int v = (t < nb) ? partial[t] : 0;
  sd[t] = v;
  __syncthreads();
  #pragma unroll
  for (int s = 1; s < 256; s <<= 1) {
    int add = (t >= s) ? sd[t - s] : 0;
    __syncthreads();
    sd[t] += add;
    __syncthreads();
  }
  if (t < nb) partial[t] = (t == 0) ? 0 : sd[t - 1];
}

__global__ __launch_bounds__(256) void scan_apply(const int* __restrict__ incl,
                                                  const int* __restrict__ partial,
                                                  int* __restrict__ off) {
  int i = blockIdx.x * 256 + threadIdx.x;
  if (i < NN) off[i + 1] = incl[i] + partial[blockIdx.x];
  if (i == 0) off[0] = 0;
}

__global__ void fill_scatter(const int* __restrict__ row, const int* __restrict__ col,
                             const float* __restrict__ ew, const int* __restrict__ off,
                             const int* __restrict__ slot, int* __restrict__ src_s,
                             float* __restrict__ ew_s) {
  int e = blockIdx.x * 256 + threadIdx.x;
  if (e < NE) {
    int idx = off[col[e]] + slot[e];
    src_s[idx] = row[e];
    ew_s[idx] = ew[e];
  }
}

// 16 lanes per node: coalesced CSR segment reads, shfl reduce
__global__ __launch_bounds__(256) void deg_csr(const int* __restrict__ off,
                                               const float* __restrict__ ew_s,
                                               float* __restrict__ dis) {
  int lane = threadIdx.x & 63;
  int sub = lane >> 4, fl = lane & 15;
  int node = (blockIdx.x * 4 + (threadIdx.x >> 6)) * 4 + sub;
  if (node >= NN) return;
  int s = off[node], e = off[node + 1];
  float acc = 0.f;
  for (int j = s + fl; j < e; j += 16) acc += ew_s[j];
  acc += __shfl_xor(acc, 8);
  acc += __shfl_xor(acc, 4);
  acc += __shfl_xor(acc, 2);
  acc += __shfl_xor(acc, 1);
  if (fl == 0) dis[node] = 1.0f / sqrtf(acc + 1.0f);
}

// 16 lanes per node
__global__ __launch_bounds__(256) void norm_fill(const int* __restrict__ off,
                                                 const int* __restrict__ src_s,
                                                 const float* __restrict__ ew_s,
                                                 const float* __restrict__ dis,
                                                 const int* __restrict__ types,
                                                 float* __restrict__ norm_s,
                                                 int* __restrict__ styp_s) {
  int lane = threadIdx.x & 63;
  int sub = lane >> 4, fl = lane & 15;
  int node = (blockIdx.x * 4 + (threadIdx.x >> 6)) * 4 + sub;
  if (node >= NN) return;
  int s = off[node], e = off[node + 1];
  float dc = dis[node];
  for (int j = s + fl; j < e; j += 16) {
    int sv = src_s[j];
    norm_s[j] = dis[sv] * ew_s[j] * dc;
    styp_s[j] = types[sv];
  }
}

// embW[t][n] = sum_k emb[t][k] * W1[n][k]   (30 x 128)
__global__ void embw_k(const float* __restrict__ emb, const float* __restrict__ W,
                       float* __restrict__ embW) {
  int tid = blockIdx.x * 256 + threadIdx.x;
  if (tid < NT * D) {
    int t = tid >> 7, n = tid & 127;
    const float* e = emb + (size_t)t * D;
    const float* w = W + (size_t)n * D;
    float acc = 0.f;
    for (int k = 0; k < D; k += 4) {
      float4 ev = *(const float4*)(e + k);
      float4 wv = *(const float4*)(w + k);
      acc += ev.x * wv.x + ev.y * wv.y + ev.z * wv.z + ev.w * wv.w;
    }
    embW[tid] = acc;
  }
}

__global__ void convW(const float* __restrict__ W, uint* __restrict__ Wbf) {
  int idx = blockIdx.x * 256 + threadIdx.x;  // 128*64
  if (idx < D * 64) {
    float2 v = ((const float2*)W)[idx];
    Wbf[idx] = pack2bf(v.x, v.y);
  }
}

// ---------------- layer 1 fused: X1 = relu(C @ embW1 + b1), bf16 row-major out ----------------

__global__ __launch_bounds__(256) void lay1_fused(const int* __restrict__ off,
                                                  const int* __restrict__ styp_s,
                                                  const float* __restrict__ norm_s,
                                                  const float* __restrict__ dis,
                                                  const int* __restrict__ types,
                                                  const float* __restrict__ embW,
                                                  const float* __restrict__ b1,
                                                  uint* __restrict__ outbf) {
  __shared__ float sE[NT * D];
  __shared__ float sC[16][32];
  __shared__ float sB[D];
  int t = threadIdx.x;
  for (int i = t; i < NT * D; i += 256) sE[i] = embW[i];
  if (t < D) sB[t] = b1[t];
  for (int i = t; i < 16 * 32; i += 256) ((float*)sC)[i] = 0.f;
  __syncthreads();
  int wave = t >> 6, lane = t & 63;
  int nodebase = blockIdx.x * 16;
  #pragma unroll
  for (int r = 0; r < 4; r++) {
    int li = wave * 4 + r;
    int node = nodebase + li;
    if (node < NN) {
      int s = off[node], e = off[node + 1];
      for (int idx = s + lane; idx < e; idx += 64)
        atomicAdd(&sC[li][styp_s[idx]], norm_s[idx]);
      if (lane == 0) {
        float dd = dis[node];
        atomicAdd(&sC[li][types[node]], dd * dd);
      }
    }
  }
  __syncthreads();
  #pragma unroll
  for (int r = 0; r < 4; r++) {
    int li = wave * 4 + r;
    int node = nodebase + li;
    if (node < NN) {
      float2 acc = *(const float2*)&sB[lane * 2];
      #pragma unroll
      for (int tt = 0; tt < NT; tt++) {
        float c = sC[li][tt];
        float2 ev = *(const float2*)&sE[tt * D + lane * 2];
        acc.x = fmaf(c, ev.x, acc.x);
        acc.y = fmaf(c, ev.y, acc.y);
      }
      acc.x = fmaxf(acc.x, 0.f);
      acc.y = fmaxf(acc.y, 0.f);
      outbf[(size_t)node * 64 + lane] = pack2bf(acc.x, acc.y);
    }
  }
}

// ---------------- node GEMM via MFMA: xw = X @ W^T (bf16 row-major in/out) ----------------

__global__ __launch_bounds__(256) void node_gemm_mfma(const uint* __restrict__ Abf,
                                                      const uint* __restrict__ Wbf,
                                                      uint* __restrict__ outbf) {
  __shared__ ushort tile[4][16][136];
  int w = threadIdx.x >> 6, lane = threadIdx.x & 63;
  int quad = lane >> 4;
  int m0 = blockIdx.x * 64 + w * 16;
  int mrow = m0 + (lane & 15);
  int arow = (mrow < NN) ? mrow : 0;
  uint4 afr[4];
  #pragma unroll
  for (int ks = 0; ks < 4; ks++)
    afr[ks] = *(const uint4*)(Abf + (size_t)arow * 64 + ks * 16 + quad * 4);
  f32x4 acc[8] = {};
  #pragma unroll
  for (int nt = 0; nt < 8; nt++) {
    int n = nt * 16 + (lane & 15);
    #pragma unroll
    for (int ks = 0; ks < 4; ks++) {
      union { uint4 u; bf16x8 v; } au, bu;
      au.u = afr[ks];
      bu.u = *(const uint4*)(Wbf + (size_t)n * 64 + ks * 16 + quad * 4);
      acc[nt] = __builtin_amdgcn_mfma_f32_16x16x32_bf16(au.v, bu.v, acc[nt], 0, 0, 0);
    }
  }
  #pragma unroll
  for (int nt = 0; nt < 8; nt++)
    #pragma unroll
    for (int i = 0; i < 4; i++)
      tile[w][quad * 4 + i][nt * 16 + (lane & 15)] = (ushort)bf16rne(acc[nt][i]);
  __builtin_amdgcn_s_waitcnt(0);  // wave-local LDS ordering (per-wave tile)
  #pragma unroll
  for (int rep = 0; rep < 4; rep++) {
    int r = rep * 4 + quad;
    int j = lane & 15;
    int node = m0 + r;
    if (node < NN) {
      uint4 v = *(const uint4*)&tile[w][r][j * 8];
      *(uint4*)(outbf + (size_t)node * 64 + j * 4) = v;
    }
  }
}

// ---------------- CSR aggregation: one wave per node, bf16 gather, 8x MLP (R8-proven) ------

__global__ __launch_bounds__(256) void aggregate(const uint* __restrict__ xw,
                                                 const int* __restrict__ off,
                                                 const int* __restrict__ src_s,
                                                 const float* __restrict__ norm_s,
                                                 const float* __restrict__ dis,
                                                 const float* __restrict__ bias, int relu,
                                                 uint* __restrict__ outbf,
                                                 float* __restrict__ outf) {
  int wave = threadIdx.x >> 6;
  int lane = threadIdx.x & 63;
  int node = blockIdx.x * 4 + wave;
  if (node >= NN) return;
  float accx = 0.f, accy = 0.f;
  int s = off[node], e = off[node + 1];
  int idx = s;
  int astart = (s + 3) & ~3;
  if (astart > e) astart = e;
  for (; idx < astart; idx++) {
    int src = src_s[idx];
    float nm = norm_s[idx];
    uint u = xw[(size_t)src * 64 + lane];
    accx = fmaf(nm, bflo(u), accx);
    accy = fmaf(nm, bfhi(u), accy);
  }
  for (; idx + 8 <= e; idx += 8) {
    int4 sa = *(const int4*)(src_s + idx);
    int4 sb = *(const int4*)(src_s + idx + 4);
    float4 na = *(const float4*)(norm_s + idx);
    float4 nb = *(const float4*)(norm_s + idx + 4);
    uint u0 = xw[(size_t)sa.x * 64 + lane];
    uint u1 = xw[(size_t)sa.y * 64 + lane];
    uint u2 = xw[(size_t)sa.z * 64 + lane];
    uint u3 = xw[(size_t)sa.w * 64 + lane];
    uint u4 = xw[(size_t)sb.x * 64 + lane];
    uint u5 = xw[(size_t)sb.y * 64 + lane];
    uint u6 = xw[(size_t)sb.z * 64 + lane];
    uint u7 = xw[(size_t)sb.w * 64 + lane];
    accx = fmaf(na.x, bflo(u0), accx);
    accy = fmaf(na.x, bfhi(u0), accy);
    accx = fmaf(na.y, bflo(u1), accx);
    accy = fmaf(na.y, bfhi(u1), accy);
    accx = fmaf(na.z, bflo(u2), accx);
    accy = fmaf(na.z, bfhi(u2), accy);
    accx = fmaf(na.w, bflo(u3), accx);
    accy = fmaf(na.w, bfhi(u3), accy);
    accx = fmaf(nb.x, bflo(u4), accx);
    accy = fmaf(nb.x, bfhi(u4), accy);
    accx = fmaf(nb.y, bflo(u5), accx);
    accy = fmaf(nb.y, bfhi(u5), accy);
    accx = fmaf(nb.z, bflo(u6), accx);
    accy = fmaf(nb.z, bfhi(u6), accy);
    accx = fmaf(nb.w, bflo(u7), accx);
    accy = fmaf(nb.w, bfhi(u7), accy);
  }
  for (; idx + 4 <= e; idx += 4) {
    int4 sr = *(const int4*)(src_s + idx);
    float4 nm = *(const float4*)(norm_s + idx);
    uint u0 = xw[(size_t)sr.x * 64 + lane];
    uint u1 = xw[(size_t)sr.y * 64 + lane];
    uint u2 = xw[(size_t)sr.z * 64 + lane];
    uint u3 = xw[(size_t)sr.w * 64 + lane];
    accx = fmaf(nm.x, bflo(u0), accx);
    accy = fmaf(nm.x, bfhi(u0), accy);
    accx = fmaf(nm.y, bflo(u1), accx);
    accy = fmaf(nm.y, bfhi(u1), accy);
    accx = fmaf(nm.z, bflo(u2), accx);
    accy = fmaf(nm.z, bfhi(u2), accy);
    accx = fmaf(nm.w, bflo(u3), accx);
    accy = fmaf(nm.w, bfhi(u3), accy);
  }
  for (; idx < e; idx++) {
    int src = src_s[idx];
    float nm = norm_s[idx];
    uint u = xw[(size_t)src * 64 + lane];
    accx = fmaf(nm, bflo(u), accx);
    accy = fmaf(nm, bfhi(u), accy);
  }
  float dd = dis[node];
  dd = dd * dd;
  {
    uint u = xw[(size_t)node * 64 + lane];
    accx = fmaf(dd, bflo(u), accx);
    accy = fmaf(dd, bfhi(u), accy);
  }
  float2 b = ((const float2*)bias)[lane];
  accx += b.x;
  accy += b.y;
  if (relu) {
    accx = fmaxf(accx, 0.f);
    accy = fmaxf(accy, 0.f);
  }
  if (outbf) outbf[(size_t)node * 64 + lane] = pack2bf(accx, accy);
  else ((float2*)outf)[(size_t)node * 64 + lane] = make_float2(accx, accy);
}

// ---------------- image GEMM via MFMA: xi = images @ W_img.T + b_img ----------------

__global__ void convA(const float* __restrict__ A, uint* __restrict__ Abf) {
  int idx = blockIdx.x * 256 + threadIdx.x;
  if (idx < 64 * IMG / 2) {
    float2 v = ((const float2*)A)[idx];
    Abf[idx] = pack2bf(v.x, v.y);
  }
}

__global__ __launch_bounds__(256) void img_mfma(const uint* __restrict__ Abf,
                                                const float* __restrict__ W,
                                                float* __restrict__ splitbuf) {
  int wv = threadIdx.x >> 6, lane = threadIdx.x & 63;
  int n = blockIdx.x * 64 + wv * 16 + (lane & 15);
  int kq = (lane >> 4) * 8;
  int k0 = blockIdx.y * 512 + kq;
  f32x4 acc[4] = {{0.f, 0.f, 0.f, 0.f}, {0.f, 0.f, 0.f, 0.f},
                  {0.f, 0.f, 0.f, 0.f}, {0.f, 0.f, 0.f, 0.f}};
  const float* wp = W + (size_t)n * IMG + k0;
  const uint* ap = Abf + (size_t)(lane & 15) * (IMG / 2) + k0 / 2;
  for (int ks = 0; ks < 512; ks += 32) {
    float4 w0 = *(const float4*)(wp + ks);
    float4 w1 = *(const float4*)(wp + ks + 4);
    union { uint4 u; bf16x8 v; } bu;
    bu.u.x = pack2bf(w0.x, w0.y);
    bu.u.y = pack2bf(w0.z, w0.w);
    bu.u.z = pack2bf(w1.x, w1.y);
    bu.u.w = pack2bf(w1.z, w1.w);
    #pragma unroll
    for (int mt = 0; mt < 4; mt++) {
      union { uint4 u; bf16x8 v; } au;
      au.u = *(const uint4*)(ap + (size_t)mt * 16 * (IMG / 2) + ks / 2);
      acc[mt] = __builtin_amdgcn_mfma_f32_16x16x32_bf16(au.v, bu.v, acc[mt], 0, 0, 0);
    }
  }
  #pragma unroll
  for (int mt = 0; mt < 4; mt++)
    #pragma unroll
    for (int i = 0; i < 4; i++) {
      int m = mt * 16 + (lane >> 4) * 4 + i;
      splitbuf[((size_t)blockIdx.y * 64 + m) * IMG + n] = acc[mt][i];
    }
}

__global__ __launch_bounds__(256) void img_reduce(const float* __restrict__ splitbuf,
                                                  const float* __restrict__ bias,
                                                  float* __restrict__ xi) {
  int idx = blockIdx.x * 256 + threadIdx.x;
  if (idx < 64 * IMG) {
    float acc = bias[idx & (IMG - 1)];
    #pragma unroll
    for (int s = 0; s < 8; s++) acc += splitbuf[(size_t)s * 64 * IMG + idx];
    xi[idx] = acc;
  }
}

// ---------------- small-M GEMM heads (R8-proven) ----------------

__global__ __launch_bounds__(256) void biasinit(float* __restrict__ out,
                                                const float* __restrict__ bias, int N) {
  int idx = blockIdx.x * 256 + threadIdx.x;
  if (idx < 64 * N) out[idx] = bias[idx % N];
}

__global__ __launch_bounds__(256) void gemm64(const float* __restrict__ A,
                                              const float* __restrict__ W,
                                              float* __restrict__ out, int N, int K,
                                              int kChunk) {
  __shared__ float xs[16][68];
  __shared__ float ws[16][68];
  int t = threadIdx.x;
  int n0 = blockIdx.x * 64;
  int k0 = blockIdx.y * kChunk;
  int kEnd = min(K, k0 + kChunk);
  int tn = t & 15;
  int tm = t >> 4;
  float acc[4][4] = {};
  for (int kt = k0; kt < kEnd; kt += 16) {
    int kc = (t & 3) * 4;
    int rr = t >> 2;
    float4 va = *(const float4*)(A + (size_t)rr * K + kt + kc);
    xs[kc + 0][rr] = va.x; xs[kc + 1][rr] = va.y; xs[kc + 2][rr] = va.z; xs[kc + 3][rr] = va.w;
    float4 vw = *(const float4*)(W + (size_t)(n0 + rr) * K + kt + kc);
    ws[kc + 0][rr] = vw.x; ws[kc + 1][rr] = vw.y; ws[kc + 2][rr] = vw.z; ws[kc + 3][rr] = vw.w;
    __syncthreads();
    #pragma unroll
    for (int k = 0; k < 16; k++) {
      float4 xv = *(const float4*)&xs[k][tm * 4];
      float4 wv = *(const float4*)&ws[k][tn * 4];
      float xm[4] = {xv.x, xv.y, xv.z, xv.w};
      float wn[4] = {wv.x, wv.y, wv.z, wv.w};
      #pragma unroll
      for (int mi = 0; mi < 4; mi++)
        #pragma unroll
        for (int ni = 0; ni < 4; ni++)
          acc[mi][ni] = fmaf(xm[mi], wn[ni], acc[mi][ni]);
    }
    __syncthreads();
  }
  #pragma unroll
  for (int mi = 0; mi < 4; mi++)
    #pragma unroll
    for (int ni = 0; ni < 4; ni++)
      atomicAdd(&out[(size_t)(tm * 4 + mi) * N + n0 + tn * 4 + ni], acc[mi][ni]);
}

// ---------------- pooling (bf16 input) + epilogue ----------------

__global__ void graph_bounds(const int* __restrict__ batch, int* __restrict__ goff) {
  int g = threadIdx.x;
  if (g <= NG) {
    int lo = 0, hi = NN;
    while (lo < hi) {
      int mid = (lo + hi) >> 1;
      if (batch[mid] < g) lo = mid + 1; else hi = mid;
    }
    goff[g] = lo;
  }
}

__global__ __launch_bounds__(64) void pool_partial_bf(const uint* __restrict__ xb,
                                                      const int* __restrict__ goff,
                                                      float* __restrict__ pooled) {
  int g = blockIdx.x;
  int chunk = blockIdx.y;  // 0..7
  int fl = threadIdx.x;    // 0..63, uint index within row
  int s = goff[g], e = goff[g + 1];
  float ax = 0.f, ay = 0.f;
  for (int i = s + chunk; i < e; i += 8) {
    uint u = xb[(size_t)i * 64 + fl];
    ax += bflo(u);
    ay += bfhi(u);
  }
  atomicAdd(&pooled[g * D + 2 * fl], ax);
  atomicAdd(&pooled[g * D + 2 * fl + 1], ay);
}

__global__ __launch_bounds__(128) void pool_finish(float* __restrict__ pooled,
                                                   const int* __restrict__ goff) {
  int g = blockIdx.x;
  int t = threadIdx.x;
  int c = goff[g + 1] - goff[g];
  pooled[g * D + t] /= fmaxf((float)c, 1.0f);
}

__global__ __launch_bounds__(256) void build_xcat(const float* __restrict__ xi,
                                                  const float* __restrict__ pooled,
                                                  float* __restrict__ xcat) {
  int idx = blockIdx.x * 256 + threadIdx.x;
  if (idx < 64 * 1056) {
    int r = idx / 1056;
    int c = idx % 1056;
    float4 v = (c < 1024) ? ((const float4*)xi)[r * 1024 + c]
                          : ((const float4*)pooled)[r * 32 + (c - 1024)];
    ((float4*)xcat)[idx] = v;
  }
}

__global__ __launch_bounds__(128) void normalize_rows(const float* __restrict__ oi_raw,
                                                      const float* __restrict__ oc_raw,
                                                      float* __restrict__ out) {
  int r = blockIdx.x;
  int t = threadIdx.x;
  const float* src = (r < 64) ? (oi_raw + r * D) : (oc_raw + (r - 64) * D);
  float v = src[t];
  __shared__ float red[128];
  red[t] = v * v;
  __syncthreads();
  for (int s = 64; s > 0; s >>= 1) {
    if (t < s) red[t] += red[t + s];
    __syncthreads();
  }
  out[r * D + t] = v / sqrtf(red[0]);
}

// ---------------- launch ----------------

extern "C" void kernel_launch(void* const* d_in, const int* in_sizes, int n_in,
                              void* d_out, int out_size, void* d_ws, size_t ws_size,
                              hipStream_t stream) {
  const float* images = (const float*)d_in[0];
  const int* node_types = (const int*)d_in[1];
  const int* erow = (const int*)d_in[2];
  const int* ecol = erow + NE;
  const float* eattr = (const float*)d_in[3];
  const int* batch = (const int*)d_in[4];
  const float* emb = (const float*)d_in[5];
  const float* W_img = (const float*)d_in[6];
  const float* b_img = (const float*)d_in[7];
  const float* W1 = (const float*)d_in[8];
  const float* b1 = (const float*)d_in[9];
  const float* W2 = (const float*)d_in[10];
  const float* b2 = (const float*)d_in[11];
  const float* W3 = (const float*)d_in[12];
  const float* b3 = (const float*)d_in[13];
  const float* Wi = (const float*)d_in[14];
  const float* bi = (const float*)d_in[15];
  const float* Wc = (const float*)d_in[16];
  const float* bc = (const float*)d_in[17];
  float* out = (float*)d_out;

  char* w = (char*)d_ws;
  auto alloc = [&](size_t bytes) -> void* {
    void* p = (void*)w;
    w += (bytes + 511) & ~(size_t)511;
    return p;
  };
  int* cnt_i = (int*)alloc(NN * 4);
  float* pooled = (float*)alloc(64 * D * 4);
  size_t zero_bytes = (size_t)(w - (char*)d_ws);  // cnt + pooled need zeroing
  int* csr_off = (int*)alloc((NN + 1) * 4);
  int* goff = (int*)alloc((NG + 1) * 4);
  int* scan_incl = (int*)alloc(NN * 4);
  int* scan_part = (int*)alloc(SCAN_BLOCKS * 4);
  int* slot = (int*)alloc((size_t)NE * 4);
  int* src_s = (int*)alloc((size_t)NE * 4);
  float* ew_s = (float*)alloc((size_t)NE * 4);
  float* norm_s = (float*)alloc((size_t)NE * 4);
  int* styp_s = (int*)alloc((size_t)NE * 4);
  float* dis = (float*)alloc(NN * 4);
  float* embW1 = (float*)alloc(NT * D * 4);
  uint* wbf2 = (uint*)alloc(D * 64 * 4);
  uint* wbf3 = (uint*)alloc(D * 64 * 4);
  uint* bufX = (uint*)alloc((size_t)NN * D * 2);      // X bf16 rows
  uint* bufB = (uint*)alloc((size_t)NN * D * 2);      // xw bf16 rows
  float* xi = (float*)alloc((size_t)64 * IMG * 4);
  float* xcat = (float*)alloc((size_t)64 * (IMG + D) * 4);
  float* oi_raw = (float*)alloc(64 * D * 4);
  float* oc_raw = (float*)alloc(64 * D * 4);
  uint* imgAbf = (uint*)alloc((size_t)64 * IMG * 2);
  float* splitbuf = (float*)alloc((size_t)8 * 64 * IMG * 4);

  hipMemsetAsync(d_ws, 0, zero_bytes, stream);

  // graph preprocessing
  edge_slot<<<NE / 256, 256, 0, stream>>>(ecol, cnt_i, slot);
  scan_blocks<<<SCAN_BLOCKS, 256, 0, stream>>>(cnt_i, scan_incl, scan_part);
  scan_partials<<<1, 256, 0, stream>>>(scan_part, SCAN_BLOCKS);
  scan_apply<<<SCAN_BLOCKS, 256, 0, stream>>>(scan_incl, scan_part, csr_off);
  fill_scatter<<<NE / 256, 256, 0, stream>>>(erow, ecol, eattr, csr_off, slot, src_s, ew_s);
  deg_csr<<<(NN + 15) / 16, 256, 0, stream>>>(csr_off, ew_s, dis);
  norm_fill<<<(NN + 15) / 16, 256, 0, stream>>>(csr_off, src_s, ew_s, dis, node_types,
                                                norm_s, styp_s);

  // layer 1 collapsed: X1 = relu(C @ (emb @ W1^T) + b1) -> bf16 rows
  embw_k<<<(NT * D + 255) / 256, 256, 0, stream>>>(emb, W1, embW1);
  lay1_fused<<<(NN + 15) / 16, 256, 0, stream>>>(csr_off, styp_s, norm_s, dis, node_types,
                                                 embW1, b1, bufX);

  // layers 2 & 3: MFMA GEMM + monolithic aggregation; layer-3 output bf16 for pooling
  convW<<<(D * 64 + 255) / 256, 256, 0, stream>>>(W2, wbf2);
  convW<<<(D * 64 + 255) / 256, 256, 0, stream>>>(W3, wbf3);
  int gblk = (NN + 63) / 64;
  node_gemm_mfma<<<gblk, 256, 0, stream>>>(bufX, wbf2, bufB);
  aggregate<<<(NN + 3) / 4, 256, 0, stream>>>(bufB, csr_off, src_s, norm_s, dis, b2, 1,
                                              bufX, (float*)0);
  node_gemm_mfma<<<gblk, 256, 0, stream>>>(bufX, wbf3, bufB);
  aggregate<<<(NN + 3) / 4, 256, 0, stream>>>(bufB, csr_off, src_s, norm_s, dis, b3, 0,
                                              bufX, (float*)0);  // bf16 X3 -> bufX

  // pooling (bf16 input)
  graph_bounds<<<1, 128, 0, stream>>>(batch, goff);
  {
    dim3 g(NG, 8);
    pool_partial_bf<<<g, 64, 0, stream>>>(bufX, goff, pooled);
  }
  pool_finish<<<NG, 128, 0, stream>>>(pooled, goff);

  // image path: xi = images @ W_img.T + b_img  (bf16 MFMA, split-k)
  convA<<<(64 * IMG / 2 + 255) / 256, 256, 0, stream>>>(images, imgAbf);
  {
    dim3 g(IMG / 64, 8);
    img_mfma<<<g, 256, 0, stream>>>(imgAbf, W_img, splitbuf);
  }
  img_reduce<<<(64 * IMG + 255) / 256, 256, 0, stream>>>(splitbuf, b_img, xi);

  // oi = normalize(xi @ Wi.T + bi)
  biasinit<<<(64 * D + 255) / 256, 256, 0, stream>>>(oi_raw, bi, D);
  {
    dim3 g(D / 64, 32);
    gemm64<<<g, 256, 0, stream>>>(xi, Wi, oi_raw, D, IMG, 128);
  }
  // oc = normalize(concat(xi, pooled) @ Wc.T + bc)
  build_xcat<<<(64 * 1056 + 255) / 256, 256, 0, stream>>>(xi, pooled, xcat);
  biasinit<<<(64 * D + 255) / 256, 256, 0, stream>>>(oc_raw, bc, D);
  {
    dim3 g(D / 64, 24);
    gemm64<<<g, 256, 0, stream>>>(xcat, Wc, oc_raw, D, IMG + D, 176);
  }
  normalize_rows<<<128, 128, 0, stream>>>(oi_raw, oc_raw, out);
}

// Round 11
// 470.707 us; speedup vs baseline: 1.1373x; 1.0155x over previous
//
#include <hip/hip_runtime.h>
#include <math.h>

#define NN 50000
#define NE 800000
#define NG 64
#define D 128
#define IMG 4096
#define NT 30
#define SCAN_BLOCKS ((NN + 255) / 256)

typedef unsigned int uint;
typedef unsigned short ushort;
typedef __attribute__((ext_vector_type(8))) __bf16 bf16x8;
typedef __attribute__((ext_vector_type(4))) float f32x4;

__device__ __forceinline__ uint bf16rne(float f) {
  uint h = __float_as_uint(f);
  return (h + 0x7fffu + ((h >> 16) & 1u)) >> 16;
}
__device__ __forceinline__ uint pack2bf(float a, float b) {
  return bf16rne(a) | (bf16rne(b) << 16);
}
__device__ __forceinline__ float bflo(uint u) { return __uint_as_float(u << 16); }
__device__ __forceinline__ float bfhi(uint u) { return __uint_as_float(u & 0xffff0000u); }

// X / xw bf16 storage: ROW-MAJOR, 64 uints (128 bf16) per node row.

// ---------------- graph preprocessing ----------------

__global__ void edge_slot(const int* __restrict__ col, int* __restrict__ cnt,
                          int* __restrict__ slot) {
  int e = blockIdx.x * 256 + threadIdx.x;
  if (e < NE) {
    int c = col[e];
    slot[e] = atomicAdd(&cnt[c], 1);
  }
}

__global__ __launch_bounds__(256) void scan_blocks(const int* __restrict__ cnt,
                                                   int* __restrict__ incl,
                                                   int* __restrict__ partial) {
  __shared__ int sd[256];
  int t = threadIdx.x;
  int i = blockIdx.x * 256 + t;
  int v = (i < NN) ? cnt[i] : 0;
  sd[t] = v;
  __syncthreads();
  #pragma unroll
  for (int s = 1; s < 256; s <<= 1) {
    int add = (t >= s) ? sd[t - s] : 0;
    __syncthreads();
    sd[t] += add;
    __syncthreads();
  }
  if (i < NN) incl[i] = sd[t];
  if (t == 255) partial[blockIdx.x] = sd[255];
}

__global__ __launch_bounds__(256) void scan_partials(int* __restrict__ partial, int nb) {
  __shared__ int sd[256];
  int t = threadIdx.x;
  int v = (t < nb) ? partial[t] : 0;
  sd[t] = v;
  __syncthreads();
  #pragma unroll
  for (int s = 1; s < 256; s <<= 1) {
    int add = (t >= s) ? sd[t - s] : 0;
    __syncthreads();
    sd[t] += add;
    __syncthreads();
  }
  if (t < nb) partial[t] = (t == 0) ? 0 : sd[t - 1];
}

__global__ __launch_bounds__(256) void scan_apply(const int* __restrict__ incl,
                                                  const int* __restrict__ partial,
                                                  int* __restrict__ off) {
  int i = blockIdx.x * 256 + threadIdx.x;
  if (i < NN) off[i + 1] = incl[i] + partial[blockIdx.x];
  if (i == 0) off[0] = 0;
}

__global__ void fill_scatter(const int* __restrict__ row, const int* __restrict__ col,
                             const float* __restrict__ ew, const int* __restrict__ off,
                             const int* __restrict__ slot, int* __restrict__ src_s,
                             float* __restrict__ ew_s) {
  int e = blockIdx.x * 256 + threadIdx.x;
  if (e < NE) {
    int idx = off[col[e]] + slot[e];
    src_s[idx] = row[e];
    ew_s[idx] = ew[e];
  }
}

// 16 lanes per node: coalesced CSR segment reads, shfl reduce
__global__ __launch_bounds__(256) void deg_csr(const int* __restrict__ off,
                                               const float* __restrict__ ew_s,
                                               float* __restrict__ dis) {
  int lane = threadIdx.x & 63;
  int sub = lane >> 4, fl = lane & 15;
  int node = (blockIdx.x * 4 + (threadIdx.x >> 6)) * 4 + sub;
  if (node >= NN) return;
  int s = off[node], e = off[node + 1];
  float acc = 0.f;
  for (int j = s + fl; j < e; j += 16) acc += ew_s[j];
  acc += __shfl_xor(acc, 8);
  acc += __shfl_xor(acc, 4);
  acc += __shfl_xor(acc, 2);
  acc += __shfl_xor(acc, 1);
  if (fl == 0) dis[node] = 1.0f / sqrtf(acc + 1.0f);
}

// 16 lanes per node
__global__ __launch_bounds__(256) void norm_fill(const int* __restrict__ off,
                                                 const int* __restrict__ src_s,
                                                 const float* __restrict__ ew_s,
                                                 const float* __restrict__ dis,
                                                 const int* __restrict__ types,
                                                 float* __restrict__ norm_s,
                                                 int* __restrict__ styp_s) {
  int lane = threadIdx.x & 63;
  int sub = lane >> 4, fl = lane & 15;
  int node = (blockIdx.x * 4 + (threadIdx.x >> 6)) * 4 + sub;
  if (node >= NN) return;
  int s = off[node], e = off[node + 1];
  float dc = dis[node];
  for (int j = s + fl; j < e; j += 16) {
    int sv = src_s[j];
    norm_s[j] = dis[sv] * ew_s[j] * dc;
    styp_s[j] = types[sv];
  }
}

// embW[t][n] = sum_k emb[t][k] * W1[n][k]   (30 x 128)
__global__ void embw_k(const float* __restrict__ emb, const float* __restrict__ W,
                       float* __restrict__ embW) {
  int tid = blockIdx.x * 256 + threadIdx.x;
  if (tid < NT * D) {
    int t = tid >> 7, n = tid & 127;
    const float* e = emb + (size_t)t * D;
    const float* w = W + (size_t)n * D;
    float acc = 0.f;
    for (int k = 0; k < D; k += 4) {
      float4 ev = *(const float4*)(e + k);
      float4 wv = *(const float4*)(w + k);
      acc += ev.x * wv.x + ev.y * wv.y + ev.z * wv.z + ev.w * wv.w;
    }
    embW[tid] = acc;
  }
}

// both W2 and W3 fp32 -> bf16 packed in one dispatch
__global__ void convW2(const float* __restrict__ W2, const float* __restrict__ W3,
                       uint* __restrict__ Wbf2, uint* __restrict__ Wbf3) {
  int idx = blockIdx.x * 256 + threadIdx.x;  // 2 * 128*64
  if (idx < 2 * D * 64) {
    const float2* src = (idx < D * 64) ? (const float2*)W2 : (const float2*)W3;
    uint* dst = (idx < D * 64) ? Wbf2 : Wbf3;
    int j = (idx < D * 64) ? idx : idx - D * 64;
    float2 v = src[j];
    dst[j] = pack2bf(v.x, v.y);
  }
}

// ---------------- layer 1 fused: X1 = relu(C @ embW1 + b1), bf16 row-major out ----------------

__global__ __launch_bounds__(256) void lay1_fused(const int* __restrict__ off,
                                                  const int* __restrict__ styp_s,
                                                  const float* __restrict__ norm_s,
                                                  const float* __restrict__ dis,
                                                  const int* __restrict__ types,
                                                  const float* __restrict__ embW,
                                                  const float* __restrict__ b1,
                                                  uint* __restrict__ outbf) {
  __shared__ float sE[NT * D];
  __shared__ float sC[16][32];
  __shared__ float sB[D];
  int t = threadIdx.x;
  for (int i = t; i < NT * D; i += 256) sE[i] = embW[i];
  if (t < D) sB[t] = b1[t];
  for (int i = t; i < 16 * 32; i += 256) ((float*)sC)[i] = 0.f;
  __syncthreads();
  int wave = t >> 6, lane = t & 63;
  int nodebase = blockIdx.x * 16;
  #pragma unroll
  for (int r = 0; r < 4; r++) {
    int li = wave * 4 + r;
    int node = nodebase + li;
    if (node < NN) {
      int s = off[node], e = off[node + 1];
      for (int idx = s + lane; idx < e; idx += 64)
        atomicAdd(&sC[li][styp_s[idx]], norm_s[idx]);
      if (lane == 0) {
        float dd = dis[node];
        atomicAdd(&sC[li][types[node]], dd * dd);
      }
    }
  }
  __syncthreads();
  #pragma unroll
  for (int r = 0; r < 4; r++) {
    int li = wave * 4 + r;
    int node = nodebase + li;
    if (node < NN) {
      float2 acc = *(const float2*)&sB[lane * 2];
      #pragma unroll
      for (int tt = 0; tt < NT; tt++) {
        float c = sC[li][tt];
        float2 ev = *(const float2*)&sE[tt * D + lane * 2];
        acc.x = fmaf(c, ev.x, acc.x);
        acc.y = fmaf(c, ev.y, acc.y);
      }
      acc.x = fmaxf(acc.x, 0.f);
      acc.y = fmaxf(acc.y, 0.f);
      outbf[(size_t)node * 64 + lane] = pack2bf(acc.x, acc.y);
    }
  }
}

// ---------------- node GEMM via MFMA: xw = X @ W^T (bf16 row-major in/out) ----------------

__global__ __launch_bounds__(256) void node_gemm_mfma(const uint* __restrict__ Abf,
                                                      const uint* __restrict__ Wbf,
                                                      uint* __restrict__ outbf) {
  __shared__ ushort tile[4][16][136];
  int w = threadIdx.x >> 6, lane = threadIdx.x & 63;
  int quad = lane >> 4;
  int m0 = blockIdx.x * 64 + w * 16;
  int mrow = m0 + (lane & 15);
  int arow = (mrow < NN) ? mrow : 0;
  uint4 afr[4];
  #pragma unroll
  for (int ks = 0; ks < 4; ks++)
    afr[ks] = *(const uint4*)(Abf + (size_t)arow * 64 + ks * 16 + quad * 4);
  f32x4 acc[8] = {};
  #pragma unroll
  for (int nt = 0; nt < 8; nt++) {
    int n = nt * 16 + (lane & 15);
    #pragma unroll
    for (int ks = 0; ks < 4; ks++) {
      union { uint4 u; bf16x8 v; } au, bu;
      au.u = afr[ks];
      bu.u = *(const uint4*)(Wbf + (size_t)n * 64 + ks * 16 + quad * 4);
      acc[nt] = __builtin_amdgcn_mfma_f32_16x16x32_bf16(au.v, bu.v, acc[nt], 0, 0, 0);
    }
  }
  #pragma unroll
  for (int nt = 0; nt < 8; nt++)
    #pragma unroll
    for (int i = 0; i < 4; i++)
      tile[w][quad * 4 + i][nt * 16 + (lane & 15)] = (ushort)bf16rne(acc[nt][i]);
  __builtin_amdgcn_s_waitcnt(0);  // wave-local LDS ordering (per-wave tile)
  #pragma unroll
  for (int rep = 0; rep < 4; rep++) {
    int r = rep * 4 + quad;
    int j = lane & 15;
    int node = m0 + r;
    if (node < NN) {
      uint4 v = *(const uint4*)&tile[w][r][j * 8];
      *(uint4*)(outbf + (size_t)node * 64 + j * 4) = v;
    }
  }
}

// ---------------- CSR aggregation v2: 2 nodes per wave (half-wave each, uint2 lanes) -------
// Each half-wave: 32 lanes x uint2 = full 256 B row; 8 gathers in flight per half,
// 16 edge-rows in flight per wave.

__global__ __launch_bounds__(256) void aggregate2(const uint* __restrict__ xw,
                                                  const int* __restrict__ off,
                                                  const int* __restrict__ src_s,
                                                  const float* __restrict__ norm_s,
                                                  const float* __restrict__ dis,
                                                  const float* __restrict__ bias, int relu,
                                                  uint* __restrict__ outbf,
                                                  float* __restrict__ outf) {
  const uint2* xw2 = (const uint2*)xw;
  int wave = threadIdx.x >> 6;
  int lane = threadIdx.x & 63;
  int half = lane >> 5;
  int fl = lane & 31;  // uint2 index within row
  int node = (blockIdx.x * 4 + wave) * 2 + half;
  if (node >= NN) return;
  float a0 = 0.f, a1 = 0.f, a2 = 0.f, a3 = 0.f;
  int s = off[node], e = off[node + 1];
  int idx = s;
  int astart = (s + 3) & ~3;
  if (astart > e) astart = e;
  for (; idx < astart; idx++) {
    float nm = norm_s[idx];
    uint2 u = xw2[(size_t)src_s[idx] * 32 + fl];
    a0 = fmaf(nm, bflo(u.x), a0);
    a1 = fmaf(nm, bfhi(u.x), a1);
    a2 = fmaf(nm, bflo(u.y), a2);
    a3 = fmaf(nm, bfhi(u.y), a3);
  }
  for (; idx + 8 <= e; idx += 8) {
    int4 sa = *(const int4*)(src_s + idx);
    int4 sb = *(const int4*)(src_s + idx + 4);
    float4 na = *(const float4*)(norm_s + idx);
    float4 nb = *(const float4*)(norm_s + idx + 4);
    uint2 u0 = xw2[(size_t)sa.x * 32 + fl];
    uint2 u1 = xw2[(size_t)sa.y * 32 + fl];
    uint2 u2 = xw2[(size_t)sa.z * 32 + fl];
    uint2 u3 = xw2[(size_t)sa.w * 32 + fl];
    uint2 u4 = xw2[(size_t)sb.x * 32 + fl];
    uint2 u5 = xw2[(size_t)sb.y * 32 + fl];
    uint2 u6 = xw2[(size_t)sb.z * 32 + fl];
    uint2 u7 = xw2[(size_t)sb.w * 32 + fl];
    a0 = fmaf(na.x, bflo(u0.x), a0); a1 = fmaf(na.x, bfhi(u0.x), a1);
    a2 = fmaf(na.x, bflo(u0.y), a2); a3 = fmaf(na.x, bfhi(u0.y), a3);
    a0 = fmaf(na.y, bflo(u1.x), a0); a1 = fmaf(na.y, bfhi(u1.x), a1);
    a2 = fmaf(na.y, bflo(u1.y), a2); a3 = fmaf(na.y, bfhi(u1.y), a3);
    a0 = fmaf(na.z, bflo(u2.x), a0); a1 = fmaf(na.z, bfhi(u2.x), a1);
    a2 = fmaf(na.z, bflo(u2.y), a2); a3 = fmaf(na.z, bfhi(u2.y), a3);
    a0 = fmaf(na.w, bflo(u3.x), a0); a1 = fmaf(na.w, bfhi(u3.x), a1);
    a2 = fmaf(na.w, bflo(u3.y), a2); a3 = fmaf(na.w, bfhi(u3.y), a3);
    a0 = fmaf(nb.x, bflo(u4.x), a0); a1 = fmaf(nb.x, bfhi(u4.x), a1);
    a2 = fmaf(nb.x, bflo(u4.y), a2); a3 = fmaf(nb.x, bfhi(u4.y), a3);
    a0 = fmaf(nb.y, bflo(u5.x), a0); a1 = fmaf(nb.y, bfhi(u5.x), a1);
    a2 = fmaf(nb.y, bflo(u5.y), a2); a3 = fmaf(nb.y, bfhi(u5.y), a3);
    a0 = fmaf(nb.z, bflo(u6.x), a0); a1 = fmaf(nb.z, bfhi(u6.x), a1);
    a2 = fmaf(nb.z, bflo(u6.y), a2); a3 = fmaf(nb.z, bfhi(u6.y), a3);
    a0 = fmaf(nb.w, bflo(u7.x), a0); a1 = fmaf(nb.w, bfhi(u7.x), a1);
    a2 = fmaf(nb.w, bflo(u7.y), a2); a3 = fmaf(nb.w, bfhi(u7.y), a3);
  }
  for (; idx + 4 <= e; idx += 4) {
    int4 sr = *(const int4*)(src_s + idx);
    float4 nm = *(const float4*)(norm_s + idx);
    uint2 u0 = xw2[(size_t)sr.x * 32 + fl];
    uint2 u1 = xw2[(size_t)sr.y * 32 + fl];
    uint2 u2 = xw2[(size_t)sr.z * 32 + fl];
    uint2 u3 = xw2[(size_t)sr.w * 32 + fl];
    a0 = fmaf(nm.x, bflo(u0.x), a0); a1 = fmaf(nm.x, bfhi(u0.x), a1);
    a2 = fmaf(nm.x, bflo(u0.y), a2); a3 = fmaf(nm.x, bfhi(u0.y), a3);
    a0 = fmaf(nm.y, bflo(u1.x), a0); a1 = fmaf(nm.y, bfhi(u1.x), a1);
    a2 = fmaf(nm.y, bflo(u1.y), a2); a3 = fmaf(nm.y, bfhi(u1.y), a3);
    a0 = fmaf(nm.z, bflo(u2.x), a0); a1 = fmaf(nm.z, bfhi(u2.x), a1);
    a2 = fmaf(nm.z, bflo(u2.y), a2); a3 = fmaf(nm.z, bfhi(u2.y), a3);
    a0 = fmaf(nm.w, bflo(u3.x), a0); a1 = fmaf(nm.w, bfhi(u3.x), a1);
    a2 = fmaf(nm.w, bflo(u3.y), a2); a3 = fmaf(nm.w, bfhi(u3.y), a3);
  }
  for (; idx < e; idx++) {
    float nm = norm_s[idx];
    uint2 u = xw2[(size_t)src_s[idx] * 32 + fl];
    a0 = fmaf(nm, bflo(u.x), a0);
    a1 = fmaf(nm, bfhi(u.x), a1);
    a2 = fmaf(nm, bflo(u.y), a2);
    a3 = fmaf(nm, bfhi(u.y), a3);
  }
  // self-loop
  float dd = dis[node];
  dd = dd * dd;
  {
    uint2 u = xw2[(size_t)node * 32 + fl];
    a0 = fmaf(dd, bflo(u.x), a0);
    a1 = fmaf(dd, bfhi(u.x), a1);
    a2 = fmaf(dd, bflo(u.y), a2);
    a3 = fmaf(dd, bfhi(u.y), a3);
  }
  float4 b = *(const float4*)(bias + 4 * fl);
  a0 += b.x; a1 += b.y; a2 += b.z; a3 += b.w;
  if (relu) {
    a0 = fmaxf(a0, 0.f);
    a1 = fmaxf(a1, 0.f);
    a2 = fmaxf(a2, 0.f);
    a3 = fmaxf(a3, 0.f);
  }
  if (outbf) {
    uint2 o;
    o.x = pack2bf(a0, a1);
    o.y = pack2bf(a2, a3);
    ((uint2*)outbf)[(size_t)node * 32 + fl] = o;
  } else {
    ((float4*)outf)[(size_t)node * 32 + fl] = make_float4(a0, a1, a2, a3);
  }
}

// ---------------- image GEMM via MFMA: xi = images @ W_img.T + b_img ----------------

__global__ void convA(const float* __restrict__ A, uint* __restrict__ Abf) {
  int idx = blockIdx.x * 256 + threadIdx.x;
  if (idx < 64 * IMG / 2) {
    float2 v = ((const float2*)A)[idx];
    Abf[idx] = pack2bf(v.x, v.y);
  }
}

__global__ __launch_bounds__(256) void img_mfma(const uint* __restrict__ Abf,
                                                const float* __restrict__ W,
                                                float* __restrict__ splitbuf) {
  int wv = threadIdx.x >> 6, lane = threadIdx.x & 63;
  int n = blockIdx.x * 64 + wv * 16 + (lane & 15);
  int kq = (lane >> 4) * 8;
  int k0 = blockIdx.y * 512 + kq;
  f32x4 acc[4] = {{0.f, 0.f, 0.f, 0.f}, {0.f, 0.f, 0.f, 0.f},
                  {0.f, 0.f, 0.f, 0.f}, {0.f, 0.f, 0.f, 0.f}};
  const float* wp = W + (size_t)n * IMG + k0;
  const uint* ap = Abf + (size_t)(lane & 15) * (IMG / 2) + k0 / 2;
  for (int ks = 0; ks < 512; ks += 32) {
    float4 w0 = *(const float4*)(wp + ks);
    float4 w1 = *(const float4*)(wp + ks + 4);
    union { uint4 u; bf16x8 v; } bu;
    bu.u.x = pack2bf(w0.x, w0.y);
    bu.u.y = pack2bf(w0.z, w0.w);
    bu.u.z = pack2bf(w1.x, w1.y);
    bu.u.w = pack2bf(w1.z, w1.w);
    #pragma unroll
    for (int mt = 0; mt < 4; mt++) {
      union { uint4 u; bf16x8 v; } au;
      au.u = *(const uint4*)(ap + (size_t)mt * 16 * (IMG / 2) + ks / 2);
      acc[mt] = __builtin_amdgcn_mfma_f32_16x16x32_bf16(au.v, bu.v, acc[mt], 0, 0, 0);
    }
  }
  #pragma unroll
  for (int mt = 0; mt < 4; mt++)
    #pragma unroll
    for (int i = 0; i < 4; i++) {
      int m = mt * 16 + (lane >> 4) * 4 + i;
      splitbuf[((size_t)blockIdx.y * 64 + m) * IMG + n] = acc[mt][i];
    }
}

__global__ __launch_bounds__(256) void img_reduce(const float* __restrict__ splitbuf,
                                                  const float* __restrict__ bias,
                                                  float* __restrict__ xi) {
  int idx = blockIdx.x * 256 + threadIdx.x;
  if (idx < 64 * IMG) {
    float acc = bias[idx & (IMG - 1)];
    #pragma unroll
    for (int s = 0; s < 8; s++) acc += splitbuf[(size_t)s * 64 * IMG + idx];
    xi[idx] = acc;
  }
}

// ---------------- small-M GEMM heads (R8-proven) ----------------

__global__ __launch_bounds__(256) void biasinit(float* __restrict__ out,
                                                const float* __restrict__ bias, int N) {
  int idx = blockIdx.x * 256 + threadIdx.x;
  if (idx < 64 * N) out[idx] = bias[idx % N];
}

__global__ __launch_bounds__(256) void gemm64(const float* __restrict__ A,
                                              const float* __restrict__ W,
                                              float* __restrict__ out, int N, int K,
                                              int kChunk) {
  __shared__ float xs[16][68];
  __shared__ float ws[16][68];
  int t = threadIdx.x;
  int n0 = blockIdx.x * 64;
  int k0 = blockIdx.y * kChunk;
  int kEnd = min(K, k0 + kChunk);
  int tn = t & 15;
  int tm = t >> 4;
  float acc[4][4] = {};
  for (int kt = k0; kt < kEnd; kt += 16) {
    int kc = (t & 3) * 4;
    int rr = t >> 2;
    float4 va = *(const float4*)(A + (size_t)rr * K + kt + kc);
    xs[kc + 0][rr] = va.x; xs[kc + 1][rr] = va.y; xs[kc + 2][rr] = va.z; xs[kc + 3][rr] = va.w;
    float4 vw = *(const float4*)(W + (size_t)(n0 + rr) * K + kt + kc);
    ws[kc + 0][rr] = vw.x; ws[kc + 1][rr] = vw.y; ws[kc + 2][rr] = vw.z; ws[kc + 3][rr] = vw.w;
    __syncthreads();
    #pragma unroll
    for (int k = 0; k < 16; k++) {
      float4 xv = *(const float4*)&xs[k][tm * 4];
      float4 wv = *(const float4*)&ws[k][tn * 4];
      float xm[4] = {xv.x, xv.y, xv.z, xv.w};
      float wn[4] = {wv.x, wv.y, wv.z, wv.w};
      #pragma unroll
      for (int mi = 0; mi < 4; mi++)
        #pragma unroll
        for (int ni = 0; ni < 4; ni++)
          acc[mi][ni] = fmaf(xm[mi], wn[ni], acc[mi][ni]);
    }
    __syncthreads();
  }
  #pragma unroll
  for (int mi = 0; mi < 4; mi++)
    #pragma unroll
    for (int ni = 0; ni < 4; ni++)
      atomicAdd(&out[(size_t)(tm * 4 + mi) * N + n0 + tn * 4 + ni], acc[mi][ni]);
}

// ---------------- pooling (bf16 input) + epilogue ----------------

__global__ void graph_bounds(const int* __restrict__ batch, int* __restrict__ goff) {
  int g = threadIdx.x;
  if (g <= NG) {
    int lo = 0, hi = NN;
    while (lo < hi) {
      int mid = (lo + hi) >> 1;
      if (batch[mid] < g) lo = mid + 1; else hi = mid;
    }
    goff[g] = lo;
  }
}

__global__ __launch_bounds__(64) void pool_partial_bf(const uint* __restrict__ xb,
                                                      const int* __restrict__ goff,
                                                      float* __restrict__ pooled) {
  int g = blockIdx.x;
  int chunk = blockIdx.y;  // 0..7
  int fl = threadIdx.x;    // 0..63, uint index within row
  int s = goff[g], e = goff[g + 1];
  float ax = 0.f, ay = 0.f;
  for (int i = s + chunk; i < e; i += 8) {
    uint u = xb[(size_t)i * 64 + fl];
    ax += bflo(u);
    ay += bfhi(u);
  }
  atomicAdd(&pooled[g * D + 2 * fl], ax);
  atomicAdd(&pooled[g * D + 2 * fl + 1], ay);
}

__global__ __launch_bounds__(128) void pool_finish(float* __restrict__ pooled,
                                                   const int* __restrict__ goff) {
  int g = blockIdx.x;
  int t = threadIdx.x;
  int c = goff[g + 1] - goff[g];
  pooled[g * D + t] /= fmaxf((float)c, 1.0f);
}

__global__ __launch_bounds__(256) void build_xcat(const float* __restrict__ xi,
                                                  const float* __restrict__ pooled,
                                                  float* __restrict__ xcat) {
  int idx = blockIdx.x * 256 + threadIdx.x;
  if (idx < 64 * 1056) {
    int r = idx / 1056;
    int c = idx % 1056;
    float4 v = (c < 1024) ? ((const float4*)xi)[r * 1024 + c]
                          : ((const float4*)pooled)[r * 32 + (c - 1024)];
    ((float4*)xcat)[idx] = v;
  }
}

__global__ __launch_bounds__(128) void normalize_rows(const float* __restrict__ oi_raw,
                                                      const float* __restrict__ oc_raw,
                                                      float* __restrict__ out) {
  int r = blockIdx.x;
  int t = threadIdx.x;
  const float* src = (r < 64) ? (oi_raw + r * D) : (oc_raw + (r - 64) * D);
  float v = src[t];
  __shared__ float red[128];
  red[t] = v * v;
  __syncthreads();
  for (int s = 64; s > 0; s >>= 1) {
    if (t < s) red[t] += red[t + s];
    __syncthreads();
  }
  out[r * D + t] = v / sqrtf(red[0]);
}

// ---------------- launch ----------------

extern "C" void kernel_launch(void* const* d_in, const int* in_sizes, int n_in,
                              void* d_out, int out_size, void* d_ws, size_t ws_size,
                              hipStream_t stream) {
  const float* images = (const float*)d_in[0];
  const int* node_types = (const int*)d_in[1];
  const int* erow = (const int*)d_in[2];
  const int* ecol = erow + NE;
  const float* eattr = (const float*)d_in[3];
  const int* batch = (const int*)d_in[4];
  const float* emb = (const float*)d_in[5];
  const float* W_img = (const float*)d_in[6];
  const float* b_img = (const float*)d_in[7];
  const float* W1 = (const float*)d_in[8];
  const float* b1 = (const float*)d_in[9];
  const float* W2 = (const float*)d_in[10];
  const float* b2 = (const float*)d_in[11];
  const float* W3 = (const float*)d_in[12];
  const float* b3 = (const float*)d_in[13];
  const float* Wi = (const float*)d_in[14];
  const float* bi = (const float*)d_in[15];
  const float* Wc = (const float*)d_in[16];
  const float* bc = (const float*)d_in[17];
  float* out = (float*)d_out;

  char* w = (char*)d_ws;
  auto alloc = [&](size_t bytes) -> void* {
    void* p = (void*)w;
    w += (bytes + 511) & ~(size_t)511;
    return p;
  };
  int* cnt_i = (int*)alloc(NN * 4);
  float* pooled = (float*)alloc(64 * D * 4);
  size_t zero_bytes = (size_t)(w - (char*)d_ws);  // cnt + pooled need zeroing
  int* csr_off = (int*)alloc((NN + 1) * 4);
  int* goff = (int*)alloc((NG + 1) * 4);
  int* scan_incl = (int*)alloc(NN * 4);
  int* scan_part = (int*)alloc(SCAN_BLOCKS * 4);
  int* slot = (int*)alloc((size_t)NE * 4);
  int* src_s = (int*)alloc((size_t)NE * 4);
  float* ew_s = (float*)alloc((size_t)NE * 4);
  float* norm_s = (float*)alloc((size_t)NE * 4);
  int* styp_s = (int*)alloc((size_t)NE * 4);
  float* dis = (float*)alloc(NN * 4);
  float* embW1 = (float*)alloc(NT * D * 4);
  uint* wbf2 = (uint*)alloc(D * 64 * 4);
  uint* wbf3 = (uint*)alloc(D * 64 * 4);
  uint* bufX = (uint*)alloc((size_t)NN * D * 2);      // X bf16 rows
  uint* bufB = (uint*)alloc((size_t)NN * D * 2);      // xw bf16 rows
  float* xi = (float*)alloc((size_t)64 * IMG * 4);
  float* xcat = (float*)alloc((size_t)64 * (IMG + D) * 4);
  float* oi_raw = (float*)alloc(64 * D * 4);
  float* oc_raw = (float*)alloc(64 * D * 4);
  uint* imgAbf = (uint*)alloc((size_t)64 * IMG * 2);
  float* splitbuf = (float*)alloc((size_t)8 * 64 * IMG * 4);

  hipMemsetAsync(d_ws, 0, zero_bytes, stream);

  // graph preprocessing
  edge_slot<<<NE / 256, 256, 0, stream>>>(ecol, cnt_i, slot);
  scan_blocks<<<SCAN_BLOCKS, 256, 0, stream>>>(cnt_i, scan_incl, scan_part);
  scan_partials<<<1, 256, 0, stream>>>(scan_part, SCAN_BLOCKS);
  scan_apply<<<SCAN_BLOCKS, 256, 0, stream>>>(scan_incl, scan_part, csr_off);
  fill_scatter<<<NE / 256, 256, 0, stream>>>(erow, ecol, eattr, csr_off, slot, src_s, ew_s);
  deg_csr<<<(NN + 15) / 16, 256, 0, stream>>>(csr_off, ew_s, dis);
  norm_fill<<<(NN + 15) / 16, 256, 0, stream>>>(csr_off, src_s, ew_s, dis, node_types,
                                                norm_s, styp_s);

  // layer 1 collapsed: X1 = relu(C @ (emb @ W1^T) + b1) -> bf16 rows
  embw_k<<<(NT * D + 255) / 256, 256, 0, stream>>>(emb, W1, embW1);
  lay1_fused<<<(NN + 15) / 16, 256, 0, stream>>>(csr_off, styp_s, norm_s, dis, node_types,
                                                 embW1, b1, bufX);

  // layers 2 & 3: MFMA GEMM + 2-node/wave aggregation; layer-3 output bf16 for pooling
  convW2<<<(2 * D * 64 + 255) / 256, 256, 0, stream>>>(W2, W3, wbf2, wbf3);
  int gblk = (NN + 63) / 64;
  int ablk = (NN + 7) / 8;
  node_gemm_mfma<<<gblk, 256, 0, stream>>>(bufX, wbf2, bufB);
  aggregate2<<<ablk, 256, 0, stream>>>(bufB, csr_off, src_s, norm_s, dis, b2, 1,
                                       bufX, (float*)0);
  node_gemm_mfma<<<gblk, 256, 0, stream>>>(bufX, wbf3, bufB);
  aggregate2<<<ablk, 256, 0, stream>>>(bufB, csr_off, src_s, norm_s, dis, b3, 0,
                                       bufX, (float*)0);  // bf16 X3 -> bufX

  // pooling (bf16 input)
  graph_bounds<<<1, 128, 0, stream>>>(batch, goff);
  {
    dim3 g(NG, 8);
    pool_partial_bf<<<g, 64, 0, stream>>>(bufX, goff, pooled);
  }
  pool_finish<<<NG, 128, 0, stream>>>(pooled, goff);

  // image path: xi = images @ W_img.T + b_img  (bf16 MFMA, split-k)
  convA<<<(64 * IMG / 2 + 255) / 256, 256, 0, stream>>>(images, imgAbf);
  {
    dim3 g(IMG / 64, 8);
    img_mfma<<<g, 256, 0, stream>>>(imgAbf, W_img, splitbuf);
  }
  img_reduce<<<(64 * IMG + 255) / 256, 256, 0, stream>>>(splitbuf, b_img, xi);

  // oi = normalize(xi @ Wi.T + bi)
  biasinit<<<(64 * D + 255) / 256, 256, 0, stream>>>(oi_raw, bi, D);
  {
    dim3 g(D / 64, 32);
    gemm64<<<g, 256, 0, stream>>>(xi, Wi, oi_raw, D, IMG, 128);
  }
  // oc = normalize(concat(xi, pooled) @ Wc.T + bc)
  build_xcat<<<(64 * 1056 + 255) / 256, 256, 0, stream>>>(xi, pooled, xcat);
  biasinit<<<(64 * D + 255) / 256, 256, 0, stream>>>(oc_raw, bc, D);
  {
    dim3 g(D / 64, 24);
    gemm64<<<g, 256, 0, stream>>>(xcat, Wc, oc_raw, D, IMG + D, 176);
  }
  normalize_rows<<<128, 128, 0, stream>>>(oi_raw, oc_raw, out);
}

// Round 12
// 458.272 us; speedup vs baseline: 1.1682x; 1.0271x over previous
//
#include <hip/hip_runtime.h>
#include <math.h>

#define NN 50000
#define NE 800000
#define NG 64
#define D 128
#define IMG 4096
#define NT 30
#define SCAN_BLOCKS ((NN + 255) / 256)

typedef unsigned int uint;
typedef unsigned short ushort;
typedef __attribute__((ext_vector_type(8))) __bf16 bf16x8;
typedef __attribute__((ext_vector_type(4))) float f32x4;

__device__ __forceinline__ uint bf16rne(float f) {
  uint h = __float_as_uint(f);
  return (h + 0x7fffu + ((h >> 16) & 1u)) >> 16;
}
__device__ __forceinline__ uint pack2bf(float a, float b) {
  return bf16rne(a) | (bf16rne(b) << 16);
}
__device__ __forceinline__ float bflo(uint u) { return __uint_as_float(u << 16); }
__device__ __forceinline__ float bfhi(uint u) { return __uint_as_float(u & 0xffff0000u); }

// X / xw bf16 storage: ROW-MAJOR, 64 uints (128 bf16) per node row.

// ---------------- graph preprocessing ----------------

__global__ void edge_slot(const int* __restrict__ col, int* __restrict__ cnt,
                          int* __restrict__ slot) {
  int e = blockIdx.x * 256 + threadIdx.x;
  if (e < NE) {
    int c = col[e];
    slot[e] = atomicAdd(&cnt[c], 1);
  }
}

__global__ __launch_bounds__(256) void scan_blocks(const int* __restrict__ cnt,
                                                   int* __restrict__ incl,
                                                   int* __restrict__ partial) {
  __shared__ int sd[256];
  int t = threadIdx.x;
  int i = blockIdx.x * 256 + t;
  int v = (i < NN) ? cnt[i] : 0;
  sd[t] = v;
  __syncthreads();
  #pragma unroll
  for (int s = 1; s < 256; s <<= 1) {
    int add = (t >= s) ? sd[t - s] : 0;
    __syncthreads();
    sd[t] += add;
    __syncthreads();
  }
  if (i < NN) incl[i] = sd[t];
  if (t == 255) partial[blockIdx.x] = sd[255];
}

__global__ __launch_bounds__(256) void scan_partials(int* __restrict__ partial, int nb) {
  __shared__ int sd[256];
  int t = threadIdx.x;
  int v = (t < nb) ? partial[t] : 0;
  sd[t] = v;
  __syncthreads();
  #pragma unroll
  for (int s = 1; s < 256; s <<= 1) {
    int add = (t >= s) ? sd[t - s] : 0;
    __syncthreads();
    sd[t] += add;
    __syncthreads();
  }
  if (t < nb) partial[t] = (t == 0) ? 0 : sd[t - 1];
}

__global__ __launch_bounds__(256) void scan_apply(const int* __restrict__ incl,
                                                  const int* __restrict__ partial,
                                                  int* __restrict__ off) {
  int i = blockIdx.x * 256 + threadIdx.x;
  if (i < NN) off[i + 1] = incl[i] + partial[blockIdx.x];
  if (i == 0) off[0] = 0;
}

// scatter packed (src, ew) -> single 8 B random store per edge
__global__ void fill_scatter(const int* __restrict__ row, const int* __restrict__ col,
                             const float* __restrict__ ew, const int* __restrict__ off,
                             const int* __restrict__ slot, int2* __restrict__ edge_se) {
  int e = blockIdx.x * 256 + threadIdx.x;
  if (e < NE) {
    int idx = off[col[e]] + slot[e];
    edge_se[idx] = make_int2(row[e], __float_as_int(ew[e]));
  }
}

// 16 lanes per node: coalesced CSR segment reads, shfl reduce
__global__ __launch_bounds__(256) void deg_csr(const int* __restrict__ off,
                                               const int2* __restrict__ edge_se,
                                               float* __restrict__ dis) {
  int lane = threadIdx.x & 63;
  int sub = lane >> 4, fl = lane & 15;
  int node = (blockIdx.x * 4 + (threadIdx.x >> 6)) * 4 + sub;
  if (node >= NN) return;
  int s = off[node], e = off[node + 1];
  float acc = 0.f;
  for (int j = s + fl; j < e; j += 16) acc += __int_as_float(edge_se[j].y);
  acc += __shfl_xor(acc, 8);
  acc += __shfl_xor(acc, 4);
  acc += __shfl_xor(acc, 2);
  acc += __shfl_xor(acc, 1);
  if (fl == 0) dis[node] = 1.0f / sqrtf(acc + 1.0f);
}

// 16 lanes per node: unpack edge_se -> src_s, norm_s, styp_s (all coalesced writes)
__global__ __launch_bounds__(256) void norm_fill(const int* __restrict__ off,
                                                 const int2* __restrict__ edge_se,
                                                 const float* __restrict__ dis,
                                                 const int* __restrict__ types,
                                                 int* __restrict__ src_s,
                                                 float* __restrict__ norm_s,
                                                 int* __restrict__ styp_s) {
  int lane = threadIdx.x & 63;
  int sub = lane >> 4, fl = lane & 15;
  int node = (blockIdx.x * 4 + (threadIdx.x >> 6)) * 4 + sub;
  if (node >= NN) return;
  int s = off[node], e = off[node + 1];
  float dc = dis[node];
  for (int j = s + fl; j < e; j += 16) {
    int2 se = edge_se[j];
    int sv = se.x;
    src_s[j] = sv;
    norm_s[j] = dis[sv] * __int_as_float(se.y) * dc;
    styp_s[j] = types[sv];
  }
}

// embW[t][n] = sum_k emb[t][k] * W1[n][k]   (30 x 128)
__global__ void embw_k(const float* __restrict__ emb, const float* __restrict__ W,
                       float* __restrict__ embW) {
  int tid = blockIdx.x * 256 + threadIdx.x;
  if (tid < NT * D) {
    int t = tid >> 7, n = tid & 127;
    const float* e = emb + (size_t)t * D;
    const float* w = W + (size_t)n * D;
    float acc = 0.f;
    for (int k = 0; k < D; k += 4) {
      float4 ev = *(const float4*)(e + k);
      float4 wv = *(const float4*)(w + k);
      acc += ev.x * wv.x + ev.y * wv.y + ev.z * wv.z + ev.w * wv.w;
    }
    embW[tid] = acc;
  }
}

// both W2 and W3 fp32 -> bf16 packed in one dispatch
__global__ void convW2(const float* __restrict__ W2, const float* __restrict__ W3,
                       uint* __restrict__ Wbf2, uint* __restrict__ Wbf3) {
  int idx = blockIdx.x * 256 + threadIdx.x;  // 2 * 128*64
  if (idx < 2 * D * 64) {
    const float2* src = (idx < D * 64) ? (const float2*)W2 : (const float2*)W3;
    uint* dst = (idx < D * 64) ? Wbf2 : Wbf3;
    int j = (idx < D * 64) ? idx : idx - D * 64;
    float2 v = src[j];
    dst[j] = pack2bf(v.x, v.y);
  }
}

// ---------------- layer 1 v2: X1 = relu(sum_e norm*embW[styp] + dis^2*embW[type] + b1) -----
// embW staged fp32 in LDS (15 KB); wave per node; ds_read_b64 per edge (conflict-free).

__global__ __launch_bounds__(256) void lay1_fused(const int* __restrict__ off,
                                                  const int* __restrict__ styp_s,
                                                  const float* __restrict__ norm_s,
                                                  const float* __restrict__ dis,
                                                  const int* __restrict__ types,
                                                  const float* __restrict__ embW,
                                                  const float* __restrict__ b1,
                                                  uint* __restrict__ outbf) {
  __shared__ float sE[NT * D];  // 15360 B
  __shared__ float sB[D];
  int t = threadIdx.x;
  for (int i = t; i < NT * D; i += 256) sE[i] = embW[i];
  if (t < D) sB[t] = b1[t];
  __syncthreads();
  int wave = t >> 6, lane = t & 63;
  #pragma unroll
  for (int r = 0; r < 4; r++) {
    int node = blockIdx.x * 16 + wave * 4 + r;
    if (node >= NN) continue;
    float ax = sB[2 * lane], ay = sB[2 * lane + 1];
    int s = off[node], e = off[node + 1];
    int idx = s;
    for (; idx + 4 <= e; idx += 4) {
      int4 st = *(const int4*)(styp_s + idx);
      float4 nm = *(const float4*)(norm_s + idx);
      float2 e0 = *(const float2*)&sE[st.x * D + 2 * lane];
      float2 e1 = *(const float2*)&sE[st.y * D + 2 * lane];
      float2 e2 = *(const float2*)&sE[st.z * D + 2 * lane];
      float2 e3 = *(const float2*)&sE[st.w * D + 2 * lane];
      ax = fmaf(nm.x, e0.x, ax); ay = fmaf(nm.x, e0.y, ay);
      ax = fmaf(nm.y, e1.x, ax); ay = fmaf(nm.y, e1.y, ay);
      ax = fmaf(nm.z, e2.x, ax); ay = fmaf(nm.z, e2.y, ay);
      ax = fmaf(nm.w, e3.x, ax); ay = fmaf(nm.w, e3.y, ay);
    }
    for (; idx < e; idx++) {
      float nm = norm_s[idx];
      float2 ev = *(const float2*)&sE[styp_s[idx] * D + 2 * lane];
      ax = fmaf(nm, ev.x, ax);
      ay = fmaf(nm, ev.y, ay);
    }
    float dd = dis[node];
    dd *= dd;
    float2 es = *(const float2*)&sE[types[node] * D + 2 * lane];
    ax = fmaf(dd, es.x, ax);
    ay = fmaf(dd, es.y, ay);
    ax = fmaxf(ax, 0.f);
    ay = fmaxf(ay, 0.f);
    outbf[(size_t)node * 64 + lane] = pack2bf(ax, ay);
  }
}

// ---------------- node GEMM via MFMA: xw = X @ W^T (bf16 row-major in/out) ----------------

__global__ __launch_bounds__(256) void node_gemm_mfma(const uint* __restrict__ Abf,
                                                      const uint* __restrict__ Wbf,
                                                      uint* __restrict__ outbf) {
  __shared__ ushort tile[4][16][136];
  int w = threadIdx.x >> 6, lane = threadIdx.x & 63;
  int quad = lane >> 4;
  int m0 = blockIdx.x * 64 + w * 16;
  int mrow = m0 + (lane & 15);
  int arow = (mrow < NN) ? mrow : 0;
  uint4 afr[4];
  #pragma unroll
  for (int ks = 0; ks < 4; ks++)
    afr[ks] = *(const uint4*)(Abf + (size_t)arow * 64 + ks * 16 + quad * 4);
  f32x4 acc[8] = {};
  #pragma unroll
  for (int nt = 0; nt < 8; nt++) {
    int n = nt * 16 + (lane & 15);
    #pragma unroll
    for (int ks = 0; ks < 4; ks++) {
      union { uint4 u; bf16x8 v; } au, bu;
      au.u = afr[ks];
      bu.u = *(const uint4*)(Wbf + (size_t)n * 64 + ks * 16 + quad * 4);
      acc[nt] = __builtin_amdgcn_mfma_f32_16x16x32_bf16(au.v, bu.v, acc[nt], 0, 0, 0);
    }
  }
  #pragma unroll
  for (int nt = 0; nt < 8; nt++)
    #pragma unroll
    for (int i = 0; i < 4; i++)
      tile[w][quad * 4 + i][nt * 16 + (lane & 15)] = (ushort)bf16rne(acc[nt][i]);
  __builtin_amdgcn_s_waitcnt(0);  // wave-local LDS ordering (per-wave tile)
  #pragma unroll
  for (int rep = 0; rep < 4; rep++) {
    int r = rep * 4 + quad;
    int j = lane & 15;
    int node = m0 + r;
    if (node < NN) {
      uint4 v = *(const uint4*)&tile[w][r][j * 8];
      *(uint4*)(outbf + (size_t)node * 64 + j * 4) = v;
    }
  }
}

// ---------------- CSR aggregation v2: 2 nodes per wave (half-wave each, uint2 lanes) -------

__global__ __launch_bounds__(256) void aggregate2(const uint* __restrict__ xw,
                                                  const int* __restrict__ off,
                                                  const int* __restrict__ src_s,
                                                  const float* __restrict__ norm_s,
                                                  const float* __restrict__ dis,
                                                  const float* __restrict__ bias, int relu,
                                                  uint* __restrict__ outbf,
                                                  float* __restrict__ outf) {
  const uint2* xw2 = (const uint2*)xw;
  int wave = threadIdx.x >> 6;
  int lane = threadIdx.x & 63;
  int half = lane >> 5;
  int fl = lane & 31;  // uint2 index within row
  int node = (blockIdx.x * 4 + wave) * 2 + half;
  if (node >= NN) return;
  float a0 = 0.f, a1 = 0.f, a2 = 0.f, a3 = 0.f;
  int s = off[node], e = off[node + 1];
  int idx = s;
  int astart = (s + 3) & ~3;
  if (astart > e) astart = e;
  for (; idx < astart; idx++) {
    float nm = norm_s[idx];
    uint2 u = xw2[(size_t)src_s[idx] * 32 + fl];
    a0 = fmaf(nm, bflo(u.x), a0);
    a1 = fmaf(nm, bfhi(u.x), a1);
    a2 = fmaf(nm, bflo(u.y), a2);
    a3 = fmaf(nm, bfhi(u.y), a3);
  }
  for (; idx + 8 <= e; idx += 8) {
    int4 sa = *(const int4*)(src_s + idx);
    int4 sb = *(const int4*)(src_s + idx + 4);
    float4 na = *(const float4*)(norm_s + idx);
    float4 nb = *(const float4*)(norm_s + idx + 4);
    uint2 u0 = xw2[(size_t)sa.x * 32 + fl];
    uint2 u1 = xw2[(size_t)sa.y * 32 + fl];
    uint2 u2 = xw2[(size_t)sa.z * 32 + fl];
    uint2 u3 = xw2[(size_t)sa.w * 32 + fl];
    uint2 u4 = xw2[(size_t)sb.x * 32 + fl];
    uint2 u5 = xw2[(size_t)sb.y * 32 + fl];
    uint2 u6 = xw2[(size_t)sb.z * 32 + fl];
    uint2 u7 = xw2[(size_t)sb.w * 32 + fl];
    a0 = fmaf(na.x, bflo(u0.x), a0); a1 = fmaf(na.x, bfhi(u0.x), a1);
    a2 = fmaf(na.x, bflo(u0.y), a2); a3 = fmaf(na.x, bfhi(u0.y), a3);
    a0 = fmaf(na.y, bflo(u1.x), a0); a1 = fmaf(na.y, bfhi(u1.x), a1);
    a2 = fmaf(na.y, bflo(u1.y), a2); a3 = fmaf(na.y, bfhi(u1.y), a3);
    a0 = fmaf(na.z, bflo(u2.x), a0); a1 = fmaf(na.z, bfhi(u2.x), a1);
    a2 = fmaf(na.z, bflo(u2.y), a2); a3 = fmaf(na.z, bfhi(u2.y), a3);
    a0 = fmaf(na.w, bflo(u3.x), a0); a1 = fmaf(na.w, bfhi(u3.x), a1);
    a2 = fmaf(na.w, bflo(u3.y), a2); a3 = fmaf(na.w, bfhi(u3.y), a3);
    a0 = fmaf(nb.x, bflo(u4.x), a0); a1 = fmaf(nb.x, bfhi(u4.x), a1);
    a2 = fmaf(nb.x, bflo(u4.y), a2); a3 = fmaf(nb.x, bfhi(u4.y), a3);
    a0 = fmaf(nb.y, bflo(u5.x), a0); a1 = fmaf(nb.y, bfhi(u5.x), a1);
    a2 = fmaf(nb.y, bflo(u5.y), a2); a3 = fmaf(nb.y, bfhi(u5.y), a3);
    a0 = fmaf(nb.z, bflo(u6.x), a0); a1 = fmaf(nb.z, bfhi(u6.x), a1);
    a2 = fmaf(nb.z, bflo(u6.y), a2); a3 = fmaf(nb.z, bfhi(u6.y), a3);
    a0 = fmaf(nb.w, bflo(u7.x), a0); a1 = fmaf(nb.w, bfhi(u7.x), a1);
    a2 = fmaf(nb.w, bflo(u7.y), a2); a3 = fmaf(nb.w, bfhi(u7.y), a3);
  }
  for (; idx + 4 <= e; idx += 4) {
    int4 sr = *(const int4*)(src_s + idx);
    float4 nm = *(const float4*)(norm_s + idx);
    uint2 u0 = xw2[(size_t)sr.x * 32 + fl];
    uint2 u1 = xw2[(size_t)sr.y * 32 + fl];
    uint2 u2 = xw2[(size_t)sr.z * 32 + fl];
    uint2 u3 = xw2[(size_t)sr.w * 32 + fl];
    a0 = fmaf(nm.x, bflo(u0.x), a0); a1 = fmaf(nm.x, bfhi(u0.x), a1);
    a2 = fmaf(nm.x, bflo(u0.y), a2); a3 = fmaf(nm.x, bfhi(u0.y), a3);
    a0 = fmaf(nm.y, bflo(u1.x), a0); a1 = fmaf(nm.y, bfhi(u1.x), a1);
    a2 = fmaf(nm.y, bflo(u1.y), a2); a3 = fmaf(nm.y, bfhi(u1.y), a3);
    a0 = fmaf(nm.z, bflo(u2.x), a0); a1 = fmaf(nm.z, bfhi(u2.x), a1);
    a2 = fmaf(nm.z, bflo(u2.y), a2); a3 = fmaf(nm.z, bfhi(u2.y), a3);
    a0 = fmaf(nm.w, bflo(u3.x), a0); a1 = fmaf(nm.w, bfhi(u3.x), a1);
    a2 = fmaf(nm.w, bflo(u3.y), a2); a3 = fmaf(nm.w, bfhi(u3.y), a3);
  }
  for (; idx < e; idx++) {
    float nm = norm_s[idx];
    uint2 u = xw2[(size_t)src_s[idx] * 32 + fl];
    a0 = fmaf(nm, bflo(u.x), a0);
    a1 = fmaf(nm, bfhi(u.x), a1);
    a2 = fmaf(nm, bflo(u.y), a2);
    a3 = fmaf(nm, bfhi(u.y), a3);
  }
  // self-loop
  float dd = dis[node];
  dd = dd * dd;
  {
    uint2 u = xw2[(size_t)node * 32 + fl];
    a0 = fmaf(dd, bflo(u.x), a0);
    a1 = fmaf(dd, bfhi(u.x), a1);
    a2 = fmaf(dd, bflo(u.y), a2);
    a3 = fmaf(dd, bfhi(u.y), a3);
  }
  float4 b = *(const float4*)(bias + 4 * fl);
  a0 += b.x; a1 += b.y; a2 += b.z; a3 += b.w;
  if (relu) {
    a0 = fmaxf(a0, 0.f);
    a1 = fmaxf(a1, 0.f);
    a2 = fmaxf(a2, 0.f);
    a3 = fmaxf(a3, 0.f);
  }
  if (outbf) {
    uint2 o;
    o.x = pack2bf(a0, a1);
    o.y = pack2bf(a2, a3);
    ((uint2*)outbf)[(size_t)node * 32 + fl] = o;
  } else {
    ((float4*)outf)[(size_t)node * 32 + fl] = make_float4(a0, a1, a2, a3);
  }
}

// ---------------- image GEMM via MFMA: xi = images @ W_img.T + b_img ----------------

__global__ void convA(const float* __restrict__ A, uint* __restrict__ Abf) {
  int idx = blockIdx.x * 256 + threadIdx.x;
  if (idx < 64 * IMG / 2) {
    float2 v = ((const float2*)A)[idx];
    Abf[idx] = pack2bf(v.x, v.y);
  }
}

__global__ __launch_bounds__(256) void img_mfma(const uint* __restrict__ Abf,
                                                const float* __restrict__ W,
                                                float* __restrict__ splitbuf) {
  int wv = threadIdx.x >> 6, lane = threadIdx.x & 63;
  int n = blockIdx.x * 64 + wv * 16 + (lane & 15);
  int kq = (lane >> 4) * 8;
  int k0 = blockIdx.y * 512 + kq;
  f32x4 acc[4] = {{0.f, 0.f, 0.f, 0.f}, {0.f, 0.f, 0.f, 0.f},
                  {0.f, 0.f, 0.f, 0.f}, {0.f, 0.f, 0.f, 0.f}};
  const float* wp = W + (size_t)n * IMG + k0;
  const uint* ap = Abf + (size_t)(lane & 15) * (IMG / 2) + k0 / 2;
  for (int ks = 0; ks < 512; ks += 32) {
    float4 w0 = *(const float4*)(wp + ks);
    float4 w1 = *(const float4*)(wp + ks + 4);
    union { uint4 u; bf16x8 v; } bu;
    bu.u.x = pack2bf(w0.x, w0.y);
    bu.u.y = pack2bf(w0.z, w0.w);
    bu.u.z = pack2bf(w1.x, w1.y);
    bu.u.w = pack2bf(w1.z, w1.w);
    #pragma unroll
    for (int mt = 0; mt < 4; mt++) {
      union { uint4 u; bf16x8 v; } au;
      au.u = *(const uint4*)(ap + (size_t)mt * 16 * (IMG / 2) + ks / 2);
      acc[mt] = __builtin_amdgcn_mfma_f32_16x16x32_bf16(au.v, bu.v, acc[mt], 0, 0, 0);
    }
  }
  #pragma unroll
  for (int mt = 0; mt < 4; mt++)
    #pragma unroll
    for (int i = 0; i < 4; i++) {
      int m = mt * 16 + (lane >> 4) * 4 + i;
      splitbuf[((size_t)blockIdx.y * 64 + m) * IMG + n] = acc[mt][i];
    }
}

__global__ __launch_bounds__(256) void img_reduce(const float* __restrict__ splitbuf,
                                                  const float* __restrict__ bias,
                                                  float* __restrict__ xi) {
  int idx = blockIdx.x * 256 + threadIdx.x;
  if (idx < 64 * IMG) {
    float acc = bias[idx & (IMG - 1)];
    #pragma unroll
    for (int s = 0; s < 8; s++) acc += splitbuf[(size_t)s * 64 * IMG + idx];
    xi[idx] = acc;
  }
}

// ---------------- small-M GEMM heads (R8-proven) ----------------

__global__ __launch_bounds__(256) void biasinit(float* __restrict__ out,
                                                const float* __restrict__ bias, int N) {
  int idx = blockIdx.x * 256 + threadIdx.x;
  if (idx < 64 * N) out[idx] = bias[idx % N];
}

__global__ __launch_bounds__(256) void gemm64(const float* __restrict__ A,
                                              const float* __restrict__ W,
                                              float* __restrict__ out, int N, int K,
                                              int kChunk) {
  __shared__ float xs[16][68];
  __shared__ float ws[16][68];
  int t = threadIdx.x;
  int n0 = blockIdx.x * 64;
  int k0 = blockIdx.y * kChunk;
  int kEnd = min(K, k0 + kChunk);
  int tn = t & 15;
  int tm = t >> 4;
  float acc[4][4] = {};
  for (int kt = k0; kt < kEnd; kt += 16) {
    int kc = (t & 3) * 4;
    int rr = t >> 2;
    float4 va = *(const float4*)(A + (size_t)rr * K + kt + kc);
    xs[kc + 0][rr] = va.x; xs[kc + 1][rr] = va.y; xs[kc + 2][rr] = va.z; xs[kc + 3][rr] = va.w;
    float4 vw = *(const float4*)(W + (size_t)(n0 + rr) * K + kt + kc);
    ws[kc + 0][rr] = vw.x; ws[kc + 1][rr] = vw.y; ws[kc + 2][rr] = vw.z; ws[kc + 3][rr] = vw.w;
    __syncthreads();
    #pragma unroll
    for (int k = 0; k < 16; k++) {
      float4 xv = *(const float4*)&xs[k][tm * 4];
      float4 wv = *(const float4*)&ws[k][tn * 4];
      float xm[4] = {xv.x, xv.y, xv.z, xv.w};
      float wn[4] = {wv.x, wv.y, wv.z, wv.w};
      #pragma unroll
      for (int mi = 0; mi < 4; mi++)
        #pragma unroll
        for (int ni = 0; ni < 4; ni++)
          acc[mi][ni] = fmaf(xm[mi], wn[ni], acc[mi][ni]);
    }
    __syncthreads();
  }
  #pragma unroll
  for (int mi = 0; mi < 4; mi++)
    #pragma unroll
    for (int ni = 0; ni < 4; ni++)
      atomicAdd(&out[(size_t)(tm * 4 + mi) * N + n0 + tn * 4 + ni], acc[mi][ni]);
}

// ---------------- pooling (bf16 input) + epilogue ----------------

__global__ void graph_bounds(const int* __restrict__ batch, int* __restrict__ goff) {
  int g = threadIdx.x;
  if (g <= NG) {
    int lo = 0, hi = NN;
    while (lo < hi) {
      int mid = (lo + hi) >> 1;
      if (batch[mid] < g) lo = mid + 1; else hi = mid;
    }
    goff[g] = lo;
  }
}

__global__ __launch_bounds__(64) void pool_partial_bf(const uint* __restrict__ xb,
                                                      const int* __restrict__ goff,
                                                      float* __restrict__ pooled) {
  int g = blockIdx.x;
  int chunk = blockIdx.y;  // 0..7
  int fl = threadIdx.x;    // 0..63, uint index within row
  int s = goff[g], e = goff[g + 1];
  float ax = 0.f, ay = 0.f;
  for (int i = s + chunk; i < e; i += 8) {
    uint u = xb[(size_t)i * 64 + fl];
    ax += bflo(u);
    ay += bfhi(u);
  }
  atomicAdd(&pooled[g * D + 2 * fl], ax);
  atomicAdd(&pooled[g * D + 2 * fl + 1], ay);
}

__global__ __launch_bounds__(128) void pool_finish(float* __restrict__ pooled,
                                                   const int* __restrict__ goff) {
  int g = blockIdx.x;
  int t = threadIdx.x;
  int c = goff[g + 1] - goff[g];
  pooled[g * D + t] /= fmaxf((float)c, 1.0f);
}

__global__ __launch_bounds__(256) void build_xcat(const float* __restrict__ xi,
                                                  const float* __restrict__ pooled,
                                                  float* __restrict__ xcat) {
  int idx = blockIdx.x * 256 + threadIdx.x;
  if (idx < 64 * 1056) {
    int r = idx / 1056;
    int c = idx % 1056;
    float4 v = (c < 1024) ? ((const float4*)xi)[r * 1024 + c]
                          : ((const float4*)pooled)[r * 32 + (c - 1024)];
    ((float4*)xcat)[idx] = v;
  }
}

__global__ __launch_bounds__(128) void normalize_rows(const float* __restrict__ oi_raw,
                                                      const float* __restrict__ oc_raw,
                                                      float* __restrict__ out) {
  int r = blockIdx.x;
  int t = threadIdx.x;
  const float* src = (r < 64) ? (oi_raw + r * D) : (oc_raw + (r - 64) * D);
  float v = src[t];
  __shared__ float red[128];
  red[t] = v * v;
  __syncthreads();
  for (int s = 64; s > 0; s >>= 1) {
    if (t < s) red[t] += red[t + s];
    __syncthreads();
  }
  out[r * D + t] = v / sqrtf(red[0]);
}

// ---------------- launch ----------------

extern "C" void kernel_launch(void* const* d_in, const int* in_sizes, int n_in,
                              void* d_out, int out_size, void* d_ws, size_t ws_size,
                              hipStream_t stream) {
  const float* images = (const float*)d_in[0];
  const int* node_types = (const int*)d_in[1];
  const int* erow = (const int*)d_in[2];
  const int* ecol = erow + NE;
  const float* eattr = (const float*)d_in[3];
  const int* batch = (const int*)d_in[4];
  const float* emb = (const float*)d_in[5];
  const float* W_img = (const float*)d_in[6];
  const float* b_img = (const float*)d_in[7];
  const float* W1 = (const float*)d_in[8];
  const float* b1 = (const float*)d_in[9];
  const float* W2 = (const float*)d_in[10];
  const float* b2 = (const float*)d_in[11];
  const float* W3 = (const float*)d_in[12];
  const float* b3 = (const float*)d_in[13];
  const float* Wi = (const float*)d_in[14];
  const float* bi = (const float*)d_in[15];
  const float* Wc = (const float*)d_in[16];
  const float* bc = (const float*)d_in[17];
  float* out = (float*)d_out;

  char* w = (char*)d_ws;
  auto alloc = [&](size_t bytes) -> void* {
    void* p = (void*)w;
    w += (bytes + 511) & ~(size_t)511;
    return p;
  };
  int* cnt_i = (int*)alloc(NN * 4);
  float* pooled = (float*)alloc(64 * D * 4);
  size_t zero_bytes = (size_t)(w - (char*)d_ws);  // cnt + pooled need zeroing
  int* csr_off = (int*)alloc((NN + 1) * 4);
  int* goff = (int*)alloc((NG + 1) * 4);
  int* scan_incl = (int*)alloc(NN * 4);
  int* scan_part = (int*)alloc(SCAN_BLOCKS * 4);
  int* slot = (int*)alloc((size_t)NE * 4);
  int2* edge_se = (int2*)alloc((size_t)NE * 8);
  int* src_s = (int*)alloc((size_t)NE * 4);
  float* norm_s = (float*)alloc((size_t)NE * 4);
  int* styp_s = (int*)alloc((size_t)NE * 4);
  float* dis = (float*)alloc(NN * 4);
  float* embW1 = (float*)alloc(NT * D * 4);
  uint* wbf2 = (uint*)alloc(D * 64 * 4);
  uint* wbf3 = (uint*)alloc(D * 64 * 4);
  uint* bufX = (uint*)alloc((size_t)NN * D * 2);      // X bf16 rows
  uint* bufB = (uint*)alloc((size_t)NN * D * 2);      // xw bf16 rows
  float* xi = (float*)alloc((size_t)64 * IMG * 4);
  float* xcat = (float*)alloc((size_t)64 * (IMG + D) * 4);
  float* oi_raw = (float*)alloc(64 * D * 4);
  float* oc_raw = (float*)alloc(64 * D * 4);
  uint* imgAbf = (uint*)alloc((size_t)64 * IMG * 2);
  float* splitbuf = (float*)alloc((size_t)8 * 64 * IMG * 4);

  hipMemsetAsync(d_ws, 0, zero_bytes, stream);

  // graph preprocessing
  edge_slot<<<NE / 256, 256, 0, stream>>>(ecol, cnt_i, slot);
  scan_blocks<<<SCAN_BLOCKS, 256, 0, stream>>>(cnt_i, scan_incl, scan_part);
  scan_partials<<<1, 256, 0, stream>>>(scan_part, SCAN_BLOCKS);
  scan_apply<<<SCAN_BLOCKS, 256, 0, stream>>>(scan_incl, scan_part, csr_off);
  fill_scatter<<<NE / 256, 256, 0, stream>>>(erow, ecol, eattr, csr_off, slot, edge_se);
  deg_csr<<<(NN + 15) / 16, 256, 0, stream>>>(csr_off, edge_se, dis);
  norm_fill<<<(NN + 15) / 16, 256, 0, stream>>>(csr_off, edge_se, dis, node_types,
                                                src_s, norm_s, styp_s);

  // layer 1 collapsed: X1 = relu(sum_e norm*embW1[styp] + self + b1) -> bf16 rows
  embw_k<<<(NT * D + 255) / 256, 256, 0, stream>>>(emb, W1, embW1);
  lay1_fused<<<(NN + 15) / 16, 256, 0, stream>>>(csr_off, styp_s, norm_s, dis, node_types,
                                                 embW1, b1, bufX);

  // layers 2 & 3: MFMA GEMM + 2-node/wave aggregation; layer-3 output bf16 for pooling
  convW2<<<(2 * D * 64 + 255) / 256, 256, 0, stream>>>(W2, W3, wbf2, wbf3);
  int gblk = (NN + 63) / 64;
  int ablk = (NN + 7) / 8;
  node_gemm_mfma<<<gblk, 256, 0, stream>>>(bufX, wbf2, bufB);
  aggregate2<<<ablk, 256, 0, stream>>>(bufB, csr_off, src_s, norm_s, dis, b2, 1,
                                       bufX, (float*)0);
  node_gemm_mfma<<<gblk, 256, 0, stream>>>(bufX, wbf3, bufB);
  aggregate2<<<ablk, 256, 0, stream>>>(bufB, csr_off, src_s, norm_s, dis, b3, 0,
                                       bufX, (float*)0);  // bf16 X3 -> bufX

  // pooling (bf16 input)
  graph_bounds<<<1, 128, 0, stream>>>(batch, goff);
  {
    dim3 g(NG, 8);
    pool_partial_bf<<<g, 64, 0, stream>>>(bufX, goff, pooled);
  }
  pool_finish<<<NG, 128, 0, stream>>>(pooled, goff);

  // image path: xi = images @ W_img.T + b_img  (bf16 MFMA, split-k)
  convA<<<(64 * IMG / 2 + 255) / 256, 256, 0, stream>>>(images, imgAbf);
  {
    dim3 g(IMG / 64, 8);
    img_mfma<<<g, 256, 0, stream>>>(imgAbf, W_img, splitbuf);
  }
  img_reduce<<<(64 * IMG + 255) / 256, 256, 0, stream>>>(splitbuf, b_img, xi);

  // oi = normalize(xi @ Wi.T + bi)
  biasinit<<<(64 * D + 255) / 256, 256, 0, stream>>>(oi_raw, bi, D);
  {
    dim3 g(D / 64, 32);
    gemm64<<<g, 256, 0, stream>>>(xi, Wi, oi_raw, D, IMG, 128);
  }
  // oc = normalize(concat(xi, pooled) @ Wc.T + bc)
  build_xcat<<<(64 * 1056 + 255) / 256, 256, 0, stream>>>(xi, pooled, xcat);
  biasinit<<<(64 * D + 255) / 256, 256, 0, stream>>>(oc_raw, bc, D);
  {
    dim3 g(D / 64, 24);
    gemm64<<<g, 256, 0, stream>>>(xcat, Wc, oc_raw, D, IMG + D, 176);
  }
  normalize_rows<<<128, 128, 0, stream>>>(oi_raw, oc_raw, out);
}

// Round 13
// 456.240 us; speedup vs baseline: 1.1734x; 1.0045x over previous
//
#include <hip/hip_runtime.h>
#include <math.h>

#define NN 50000
#define NE 800000
#define NG 64
#define D 128
#define IMG 4096
#define NT 30
#define NB8 (NN * 8)
#define SCAN8_BLOCKS ((NB8 + 255) / 256)

typedef unsigned int uint;
typedef unsigned short ushort;
typedef __attribute__((ext_vector_type(8))) __bf16 bf16x8;
typedef __attribute__((ext_vector_type(4))) float f32x4;

__device__ __forceinline__ uint bf16rne(float f) {
  uint h = __float_as_uint(f);
  return (h + 0x7fffu + ((h >> 16) & 1u)) >> 16;
}
__device__ __forceinline__ uint pack2bf(float a, float b) {
  return bf16rne(a) | (bf16rne(b) << 16);
}
__device__ __forceinline__ float bflo(uint u) { return __uint_as_float(u << 16); }
__device__ __forceinline__ float bfhi(uint u) { return __uint_as_float(u & 0xffff0000u); }

// X / xw bf16 storage: ROW-MAJOR, 64 uints (128 bf16) per node row.

// ---------------- graph preprocessing ----------------
// 8 sub-buckets per node to cut atomic contention; CSR = consecutive buckets.

__global__ void edge_slot(const int* __restrict__ col, int* __restrict__ cnt8,
                          int* __restrict__ slot) {
  int e = blockIdx.x * 256 + threadIdx.x;
  if (e < NE) {
    int c = col[e];
    slot[e] = atomicAdd(&cnt8[c * 8 + (e & 7)], 1);
  }
}

__global__ __launch_bounds__(256) void scan_blocks(const int* __restrict__ cnt,
                                                   int* __restrict__ incl,
                                                   int* __restrict__ partial) {
  __shared__ int sd[256];
  int t = threadIdx.x;
  int i = blockIdx.x * 256 + t;
  int v = (i < NB8) ? cnt[i] : 0;
  sd[t] = v;
  __syncthreads();
  #pragma unroll
  for (int s = 1; s < 256; s <<= 1) {
    int add = (t >= s) ? sd[t - s] : 0;
    __syncthreads();
    sd[t] += add;
    __syncthreads();
  }
  if (i < NB8) incl[i] = sd[t];
  if (t == 255) partial[blockIdx.x] = sd[255];
}

// looped exclusive scan of partial[nb] (nb up to a few thousand)
__global__ __launch_bounds__(256) void scan_partials(int* __restrict__ partial, int nb) {
  __shared__ int sd[256];
  __shared__ int sbase;
  int t = threadIdx.x;
  if (t == 0) sbase = 0;
  __syncthreads();
  for (int chunk = 0; chunk < nb; chunk += 256) {
    int i = chunk + t;
    int v = (i < nb) ? partial[i] : 0;
    sd[t] = v;
    __syncthreads();
    #pragma unroll
    for (int s = 1; s < 256; s <<= 1) {
      int add = (t >= s) ? sd[t - s] : 0;
      __syncthreads();
      sd[t] += add;
      __syncthreads();
    }
    int base = sbase;
    if (i < nb) partial[i] = base + sd[t] - v;  // exclusive
    __syncthreads();
    if (t == 255) sbase = base + sd[255];
    __syncthreads();
  }
}

__global__ __launch_bounds__(256) void scan_apply8(const int* __restrict__ incl,
                                                   const int* __restrict__ cnt8,
                                                   const int* __restrict__ partial,
                                                   int* __restrict__ ex8,
                                                   int* __restrict__ csr_off) {
  int i = blockIdx.x * 256 + threadIdx.x;
  if (i < NB8) {
    int ex = incl[i] - cnt8[i] + partial[blockIdx.x];
    ex8[i] = ex;
    if ((i & 7) == 0) csr_off[i >> 3] = ex;
  }
  if (i == 0) csr_off[NN] = NE;
}

// scatter packed (src, ew) -> single 8 B random store per edge
__global__ void fill_scatter(const int* __restrict__ row, const int* __restrict__ col,
                             const float* __restrict__ ew, const int* __restrict__ ex8,
                             const int* __restrict__ slot, int2* __restrict__ edge_se) {
  int e = blockIdx.x * 256 + threadIdx.x;
  if (e < NE) {
    int idx = ex8[col[e] * 8 + (e & 7)] + slot[e];
    edge_se[idx] = make_int2(row[e], __float_as_int(ew[e]));
  }
}

// 16 lanes per node: coalesced CSR segment reads, shfl reduce
__global__ __launch_bounds__(256) void deg_csr(const int* __restrict__ off,
                                               const int2* __restrict__ edge_se,
                                               float* __restrict__ dis) {
  int lane = threadIdx.x & 63;
  int sub = lane >> 4, fl = lane & 15;
  int node = (blockIdx.x * 4 + (threadIdx.x >> 6)) * 4 + sub;
  if (node >= NN) return;
  int s = off[node], e = off[node + 1];
  float acc = 0.f;
  for (int j = s + fl; j < e; j += 16) acc += __int_as_float(edge_se[j].y);
  acc += __shfl_xor(acc, 8);
  acc += __shfl_xor(acc, 4);
  acc += __shfl_xor(acc, 2);
  acc += __shfl_xor(acc, 1);
  if (fl == 0) dis[node] = 1.0f / sqrtf(acc + 1.0f);
}

// 16 lanes per node: unpack edge_se -> src_s, norm_s, styp_s (all coalesced writes)
__global__ __launch_bounds__(256) void norm_fill(const int* __restrict__ off,
                                                 const int2* __restrict__ edge_se,
                                                 const float* __restrict__ dis,
                                                 const int* __restrict__ types,
                                                 int* __restrict__ src_s,
                                                 float* __restrict__ norm_s,
                                                 int* __restrict__ styp_s) {
  int lane = threadIdx.x & 63;
  int sub = lane >> 4, fl = lane & 15;
  int node = (blockIdx.x * 4 + (threadIdx.x >> 6)) * 4 + sub;
  if (node >= NN) return;
  int s = off[node], e = off[node + 1];
  float dc = dis[node];
  for (int j = s + fl; j < e; j += 16) {
    int2 se = edge_se[j];
    int sv = se.x;
    src_s[j] = sv;
    norm_s[j] = dis[sv] * __int_as_float(se.y) * dc;
    styp_s[j] = types[sv];
  }
}

// fused: embW1 = emb @ W1^T (30x128)  +  W2/W3 fp32 -> bf16 pack
__global__ __launch_bounds__(256) void prep_weights(const float* __restrict__ emb,
                                                    const float* __restrict__ W1,
                                                    float* __restrict__ embW,
                                                    const float* __restrict__ W2,
                                                    const float* __restrict__ W3,
                                                    uint* __restrict__ Wbf2,
                                                    uint* __restrict__ Wbf3) {
  int tid = blockIdx.x * 256 + threadIdx.x;
  if (tid < NT * D) {
    int t = tid >> 7, n = tid & 127;
    const float* e = emb + (size_t)t * D;
    const float* w = W1 + (size_t)n * D;
    float acc = 0.f;
    for (int k = 0; k < D; k += 4) {
      float4 ev = *(const float4*)(e + k);
      float4 wv = *(const float4*)(w + k);
      acc += ev.x * wv.x + ev.y * wv.y + ev.z * wv.z + ev.w * wv.w;
    }
    embW[tid] = acc;
  } else if (tid < NT * D + D * 64) {
    int j = tid - NT * D;
    float2 v = ((const float2*)W2)[j];
    Wbf2[j] = pack2bf(v.x, v.y);
  } else if (tid < NT * D + 2 * D * 64) {
    int j = tid - NT * D - D * 64;
    float2 v = ((const float2*)W3)[j];
    Wbf3[j] = pack2bf(v.x, v.y);
  }
}

// ---------------- layer 1: X1 = relu(sum_e norm*embW[styp] + dis^2*embW[type] + b1) -----

__global__ __launch_bounds__(256) void lay1_fused(const int* __restrict__ off,
                                                  const int* __restrict__ styp_s,
                                                  const float* __restrict__ norm_s,
                                                  const float* __restrict__ dis,
                                                  const int* __restrict__ types,
                                                  const float* __restrict__ embW,
                                                  const float* __restrict__ b1,
                                                  uint* __restrict__ outbf) {
  __shared__ float sE[NT * D];  // 15360 B
  __shared__ float sB[D];
  int t = threadIdx.x;
  for (int i = t; i < NT * D; i += 256) sE[i] = embW[i];
  if (t < D) sB[t] = b1[t];
  __syncthreads();
  int wave = t >> 6, lane = t & 63;
  #pragma unroll
  for (int r = 0; r < 4; r++) {
    int node = blockIdx.x * 16 + wave * 4 + r;
    if (node >= NN) continue;
    float ax = sB[2 * lane], ay = sB[2 * lane + 1];
    int s = off[node], e = off[node + 1];
    int idx = s;
    for (; idx + 4 <= e; idx += 4) {
      int4 st = *(const int4*)(styp_s + idx);
      float4 nm = *(const float4*)(norm_s + idx);
      float2 e0 = *(const float2*)&sE[st.x * D + 2 * lane];
      float2 e1 = *(const float2*)&sE[st.y * D + 2 * lane];
      float2 e2 = *(const float2*)&sE[st.z * D + 2 * lane];
      float2 e3 = *(const float2*)&sE[st.w * D + 2 * lane];
      ax = fmaf(nm.x, e0.x, ax); ay = fmaf(nm.x, e0.y, ay);
      ax = fmaf(nm.y, e1.x, ax); ay = fmaf(nm.y, e1.y, ay);
      ax = fmaf(nm.z, e2.x, ax); ay = fmaf(nm.z, e2.y, ay);
      ax = fmaf(nm.w, e3.x, ax); ay = fmaf(nm.w, e3.y, ay);
    }
    for (; idx < e; idx++) {
      float nm = norm_s[idx];
      float2 ev = *(const float2*)&sE[styp_s[idx] * D + 2 * lane];
      ax = fmaf(nm, ev.x, ax);
      ay = fmaf(nm, ev.y, ay);
    }
    float dd = dis[node];
    dd *= dd;
    float2 es = *(const float2*)&sE[types[node] * D + 2 * lane];
    ax = fmaf(dd, es.x, ax);
    ay = fmaf(dd, es.y, ay);
    ax = fmaxf(ax, 0.f);
    ay = fmaxf(ay, 0.f);
    outbf[(size_t)node * 64 + lane] = pack2bf(ax, ay);
  }
}

// ---------------- node GEMM via MFMA: xw = X @ W^T (bf16 row-major in/out) ----------------

__global__ __launch_bounds__(256) void node_gemm_mfma(const uint* __restrict__ Abf,
                                                      const uint* __restrict__ Wbf,
                                                      uint* __restrict__ outbf) {
  __shared__ ushort tile[4][16][136];
  int w = threadIdx.x >> 6, lane = threadIdx.x & 63;
  int quad = lane >> 4;
  int m0 = blockIdx.x * 64 + w * 16;
  int mrow = m0 + (lane & 15);
  int arow = (mrow < NN) ? mrow : 0;
  uint4 afr[4];
  #pragma unroll
  for (int ks = 0; ks < 4; ks++)
    afr[ks] = *(const uint4*)(Abf + (size_t)arow * 64 + ks * 16 + quad * 4);
  f32x4 acc[8] = {};
  #pragma unroll
  for (int nt = 0; nt < 8; nt++) {
    int n = nt * 16 + (lane & 15);
    #pragma unroll
    for (int ks = 0; ks < 4; ks++) {
      union { uint4 u; bf16x8 v; } au, bu;
      au.u = afr[ks];
      bu.u = *(const uint4*)(Wbf + (size_t)n * 64 + ks * 16 + quad * 4);
      acc[nt] = __builtin_amdgcn_mfma_f32_16x16x32_bf16(au.v, bu.v, acc[nt], 0, 0, 0);
    }
  }
  #pragma unroll
  for (int nt = 0; nt < 8; nt++)
    #pragma unroll
    for (int i = 0; i < 4; i++)
      tile[w][quad * 4 + i][nt * 16 + (lane & 15)] = (ushort)bf16rne(acc[nt][i]);
  __builtin_amdgcn_s_waitcnt(0);  // wave-local LDS ordering (per-wave tile)
  #pragma unroll
  for (int rep = 0; rep < 4; rep++) {
    int r = rep * 4 + quad;
    int j = lane & 15;
    int node = m0 + r;
    if (node < NN) {
      uint4 v = *(const uint4*)&tile[w][r][j * 8];
      *(uint4*)(outbf + (size_t)node * 64 + j * 4) = v;
    }
  }
}

// ---------------- CSR aggregation v2: 2 nodes per wave (half-wave each, uint2 lanes) -------

__global__ __launch_bounds__(256) void aggregate2(const uint* __restrict__ xw,
                                                  const int* __restrict__ off,
                                                  const int* __restrict__ src_s,
                                                  const float* __restrict__ norm_s,
                                                  const float* __restrict__ dis,
                                                  const float* __restrict__ bias, int relu,
                                                  uint* __restrict__ outbf,
                                                  float* __restrict__ outf) {
  const uint2* xw2 = (const uint2*)xw;
  int wave = threadIdx.x >> 6;
  int lane = threadIdx.x & 63;
  int half = lane >> 5;
  int fl = lane & 31;  // uint2 index within row
  int node = (blockIdx.x * 4 + wave) * 2 + half;
  if (node >= NN) return;
  float a0 = 0.f, a1 = 0.f, a2 = 0.f, a3 = 0.f;
  int s = off[node], e = off[node + 1];
  int idx = s;
  int astart = (s + 3) & ~3;
  if (astart > e) astart = e;
  for (; idx < astart; idx++) {
    float nm = norm_s[idx];
    uint2 u = xw2[(size_t)src_s[idx] * 32 + fl];
    a0 = fmaf(nm, bflo(u.x), a0);
    a1 = fmaf(nm, bfhi(u.x), a1);
    a2 = fmaf(nm, bflo(u.y), a2);
    a3 = fmaf(nm, bfhi(u.y), a3);
  }
  for (; idx + 8 <= e; idx += 8) {
    int4 sa = *(const int4*)(src_s + idx);
    int4 sb = *(const int4*)(src_s + idx + 4);
    float4 na = *(const float4*)(norm_s + idx);
    float4 nb = *(const float4*)(norm_s + idx + 4);
    uint2 u0 = xw2[(size_t)sa.x * 32 + fl];
    uint2 u1 = xw2[(size_t)sa.y * 32 + fl];
    uint2 u2 = xw2[(size_t)sa.z * 32 + fl];
    uint2 u3 = xw2[(size_t)sa.w * 32 + fl];
    uint2 u4 = xw2[(size_t)sb.x * 32 + fl];
    uint2 u5 = xw2[(size_t)sb.y * 32 + fl];
    uint2 u6 = xw2[(size_t)sb.z * 32 + fl];
    uint2 u7 = xw2[(size_t)sb.w * 32 + fl];
    a0 = fmaf(na.x, bflo(u0.x), a0); a1 = fmaf(na.x, bfhi(u0.x), a1);
    a2 = fmaf(na.x, bflo(u0.y), a2); a3 = fmaf(na.x, bfhi(u0.y), a3);
    a0 = fmaf(na.y, bflo(u1.x), a0); a1 = fmaf(na.y, bfhi(u1.x), a1);
    a2 = fmaf(na.y, bflo(u1.y), a2); a3 = fmaf(na.y, bfhi(u1.y), a3);
    a0 = fmaf(na.z, bflo(u2.x), a0); a1 = fmaf(na.z, bfhi(u2.x), a1);
    a2 = fmaf(na.z, bflo(u2.y), a2); a3 = fmaf(na.z, bfhi(u2.y), a3);
    a0 = fmaf(na.w, bflo(u3.x), a0); a1 = fmaf(na.w, bfhi(u3.x), a1);
    a2 = fmaf(na.w, bflo(u3.y), a2); a3 = fmaf(na.w, bfhi(u3.y), a3);
    a0 = fmaf(nb.x, bflo(u4.x), a0); a1 = fmaf(nb.x, bfhi(u4.x), a1);
    a2 = fmaf(nb.x, bflo(u4.y), a2); a3 = fmaf(nb.x, bfhi(u4.y), a3);
    a0 = fmaf(nb.y, bflo(u5.x), a0); a1 = fmaf(nb.y, bfhi(u5.x), a1);
    a2 = fmaf(nb.y, bflo(u5.y), a2); a3 = fmaf(nb.y, bfhi(u5.y), a3);
    a0 = fmaf(nb.z, bflo(u6.x), a0); a1 = fmaf(nb.z, bfhi(u6.x), a1);
    a2 = fmaf(nb.z, bflo(u6.y), a2); a3 = fmaf(nb.z, bfhi(u6.y), a3);
    a0 = fmaf(nb.w, bflo(u7.x), a0); a1 = fmaf(nb.w, bfhi(u7.x), a1);
    a2 = fmaf(nb.w, bflo(u7.y), a2); a3 = fmaf(nb.w, bfhi(u7.y), a3);
  }
  for (; idx + 4 <= e; idx += 4) {
    int4 sr = *(const int4*)(src_s + idx);
    float4 nm = *(const float4*)(norm_s + idx);
    uint2 u0 = xw2[(size_t)sr.x * 32 + fl];
    uint2 u1 = xw2[(size_t)sr.y * 32 + fl];
    uint2 u2 = xw2[(size_t)sr.z * 32 + fl];
    uint2 u3 = xw2[(size_t)sr.w * 32 + fl];
    a0 = fmaf(nm.x, bflo(u0.x), a0); a1 = fmaf(nm.x, bfhi(u0.x), a1);
    a2 = fmaf(nm.x, bflo(u0.y), a2); a3 = fmaf(nm.x, bfhi(u0.y), a3);
    a0 = fmaf(nm.y, bflo(u1.x), a0); a1 = fmaf(nm.y, bfhi(u1.x), a1);
    a2 = fmaf(nm.y, bflo(u1.y), a2); a3 = fmaf(nm.y, bfhi(u1.y), a3);
    a0 = fmaf(nm.z, bflo(u2.x), a0); a1 = fmaf(nm.z, bfhi(u2.x), a1);
    a2 = fmaf(nm.z, bflo(u2.y), a2); a3 = fmaf(nm.z, bfhi(u2.y), a3);
    a0 = fmaf(nm.w, bflo(u3.x), a0); a1 = fmaf(nm.w, bfhi(u3.x), a1);
    a2 = fmaf(nm.w, bflo(u3.y), a2); a3 = fmaf(nm.w, bfhi(u3.y), a3);
  }
  for (; idx < e; idx++) {
    float nm = norm_s[idx];
    uint2 u = xw2[(size_t)src_s[idx] * 32 + fl];
    a0 = fmaf(nm, bflo(u.x), a0);
    a1 = fmaf(nm, bfhi(u.x), a1);
    a2 = fmaf(nm, bflo(u.y), a2);
    a3 = fmaf(nm, bfhi(u.y), a3);
  }
  // self-loop
  float dd = dis[node];
  dd = dd * dd;
  {
    uint2 u = xw2[(size_t)node * 32 + fl];
    a0 = fmaf(dd, bflo(u.x), a0);
    a1 = fmaf(dd, bfhi(u.x), a1);
    a2 = fmaf(dd, bflo(u.y), a2);
    a3 = fmaf(dd, bfhi(u.y), a3);
  }
  float4 b = *(const float4*)(bias + 4 * fl);
  a0 += b.x; a1 += b.y; a2 += b.z; a3 += b.w;
  if (relu) {
    a0 = fmaxf(a0, 0.f);
    a1 = fmaxf(a1, 0.f);
    a2 = fmaxf(a2, 0.f);
    a3 = fmaxf(a3, 0.f);
  }
  if (outbf) {
    uint2 o;
    o.x = pack2bf(a0, a1);
    o.y = pack2bf(a2, a3);
    ((uint2*)outbf)[(size_t)node * 32 + fl] = o;
  } else {
    ((float4*)outf)[(size_t)node * 32 + fl] = make_float4(a0, a1, a2, a3);
  }
}

// ---------------- image GEMM via MFMA: xi = images @ W_img.T + b_img ----------------

__global__ void convA(const float* __restrict__ A, uint* __restrict__ Abf) {
  int idx = blockIdx.x * 256 + threadIdx.x;
  if (idx < 64 * IMG / 2) {
    float2 v = ((const float2*)A)[idx];
    Abf[idx] = pack2bf(v.x, v.y);
  }
}

__global__ __launch_bounds__(256) void img_mfma(const uint* __restrict__ Abf,
                                                const float* __restrict__ W,
                                                float* __restrict__ splitbuf) {
  int wv = threadIdx.x >> 6, lane = threadIdx.x & 63;
  int n = blockIdx.x * 64 + wv * 16 + (lane & 15);
  int kq = (lane >> 4) * 8;
  int k0 = blockIdx.y * 512 + kq;
  f32x4 acc[4] = {{0.f, 0.f, 0.f, 0.f}, {0.f, 0.f, 0.f, 0.f},
                  {0.f, 0.f, 0.f, 0.f}, {0.f, 0.f, 0.f, 0.f}};
  const float* wp = W + (size_t)n * IMG + k0;
  const uint* ap = Abf + (size_t)(lane & 15) * (IMG / 2) + k0 / 2;
  for (int ks = 0; ks < 512; ks += 32) {
    float4 w0 = *(const float4*)(wp + ks);
    float4 w1 = *(const float4*)(wp + ks + 4);
    union { uint4 u; bf16x8 v; } bu;
    bu.u.x = pack2bf(w0.x, w0.y);
    bu.u.y = pack2bf(w0.z, w0.w);
    bu.u.z = pack2bf(w1.x, w1.y);
    bu.u.w = pack2bf(w1.z, w1.w);
    #pragma unroll
    for (int mt = 0; mt < 4; mt++) {
      union { uint4 u; bf16x8 v; } au;
      au.u = *(const uint4*)(ap + (size_t)mt * 16 * (IMG / 2) + ks / 2);
      acc[mt] = __builtin_amdgcn_mfma_f32_16x16x32_bf16(au.v, bu.v, acc[mt], 0, 0, 0);
    }
  }
  #pragma unroll
  for (int mt = 0; mt < 4; mt++)
    #pragma unroll
    for (int i = 0; i < 4; i++) {
      int m = mt * 16 + (lane >> 4) * 4 + i;
      splitbuf[((size_t)blockIdx.y * 64 + m) * IMG + n] = acc[mt][i];
    }
}

__global__ __launch_bounds__(256) void img_reduce(const float* __restrict__ splitbuf,
                                                  const float* __restrict__ bias,
                                                  float* __restrict__ xi) {
  int idx = blockIdx.x * 256 + threadIdx.x;
  if (idx < 64 * IMG) {
    float acc = bias[idx & (IMG - 1)];
    #pragma unroll
    for (int s = 0; s < 8; s++) acc += splitbuf[(size_t)s * 64 * IMG + idx];
    xi[idx] = acc;
  }
}

// ---------------- small-M GEMM heads: bias folded into k0 block; out pre-zeroed ------------

__global__ __launch_bounds__(256) void gemm64(const float* __restrict__ A,
                                              const float* __restrict__ W,
                                              const float* __restrict__ bias,
                                              float* __restrict__ out, int N, int K,
                                              int kChunk) {
  __shared__ float xs[16][68];
  __shared__ float ws[16][68];
  int t = threadIdx.x;
  int n0 = blockIdx.x * 64;
  int k0 = blockIdx.y * kChunk;
  int kEnd = min(K, k0 + kChunk);
  int tn = t & 15;
  int tm = t >> 4;
  float acc[4][4] = {};
  if (blockIdx.y == 0) {
    #pragma unroll
    for (int ni = 0; ni < 4; ni++) {
      float bv = bias[n0 + tn * 4 + ni];
      #pragma unroll
      for (int mi = 0; mi < 4; mi++) acc[mi][ni] = bv;
    }
  }
  for (int kt = k0; kt < kEnd; kt += 16) {
    int kc = (t & 3) * 4;
    int rr = t >> 2;
    float4 va = *(const float4*)(A + (size_t)rr * K + kt + kc);
    xs[kc + 0][rr] = va.x; xs[kc + 1][rr] = va.y; xs[kc + 2][rr] = va.z; xs[kc + 3][rr] = va.w;
    float4 vw = *(const float4*)(W + (size_t)(n0 + rr) * K + kt + kc);
    ws[kc + 0][rr] = vw.x; ws[kc + 1][rr] = vw.y; ws[kc + 2][rr] = vw.z; ws[kc + 3][rr] = vw.w;
    __syncthreads();
    #pragma unroll
    for (int k = 0; k < 16; k++) {
      float4 xv = *(const float4*)&xs[k][tm * 4];
      float4 wv = *(const float4*)&ws[k][tn * 4];
      float xm[4] = {xv.x, xv.y, xv.z, xv.w};
      float wn[4] = {wv.x, wv.y, wv.z, wv.w};
      #pragma unroll
      for (int mi = 0; mi < 4; mi++)
        #pragma unroll
        for (int ni = 0; ni < 4; ni++)
          acc[mi][ni] = fmaf(xm[mi], wn[ni], acc[mi][ni]);
    }
    __syncthreads();
  }
  #pragma unroll
  for (int mi = 0; mi < 4; mi++)
    #pragma unroll
    for (int ni = 0; ni < 4; ni++)
      atomicAdd(&out[(size_t)(tm * 4 + mi) * N + n0 + tn * 4 + ni], acc[mi][ni]);
}

// ---------------- pooling (bf16 input) + epilogue ----------------

__global__ void graph_bounds(const int* __restrict__ batch, int* __restrict__ goff) {
  int g = threadIdx.x;
  if (g <= NG) {
    int lo = 0, hi = NN;
    while (lo < hi) {
      int mid = (lo + hi) >> 1;
      if (batch[mid] < g) lo = mid + 1; else hi = mid;
    }
    goff[g] = lo;
  }
}

__global__ __launch_bounds__(64) void pool_partial_bf(const uint* __restrict__ xb,
                                                      const int* __restrict__ goff,
                                                      float* __restrict__ pooled) {
  int g = blockIdx.x;
  int chunk = blockIdx.y;  // 0..7
  int fl = threadIdx.x;    // 0..63, uint index within row
  int s = goff[g], e = goff[g + 1];
  float ax = 0.f, ay = 0.f;
  for (int i = s + chunk; i < e; i += 8) {
    uint u = xb[(size_t)i * 64 + fl];
    ax += bflo(u);
    ay += bfhi(u);
  }
  atomicAdd(&pooled[g * D + 2 * fl], ax);
  atomicAdd(&pooled[g * D + 2 * fl + 1], ay);
}

// xcat = [xi | pooled/count]; divide folded here (pool_finish dropped)
__global__ __launch_bounds__(256) void build_xcat(const float* __restrict__ xi,
                                                  const float* __restrict__ pooled,
                                                  const int* __restrict__ goff,
                                                  float* __restrict__ xcat) {
  int idx = blockIdx.x * 256 + threadIdx.x;
  if (idx < 64 * 1056) {
    int r = idx / 1056;
    int c = idx % 1056;
    float4 v;
    if (c < 1024) {
      v = ((const float4*)xi)[r * 1024 + c];
    } else {
      v = ((const float4*)pooled)[r * 32 + (c - 1024)];
      float inv = 1.0f / fmaxf((float)(goff[r + 1] - goff[r]), 1.0f);
      v.x *= inv; v.y *= inv; v.z *= inv; v.w *= inv;
    }
    ((float4*)xcat)[idx] = v;
  }
}

__global__ __launch_bounds__(128) void normalize_rows(const float* __restrict__ oi_raw,
                                                      const float* __restrict__ oc_raw,
                                                      float* __restrict__ out) {
  int r = blockIdx.x;
  int t = threadIdx.x;
  const float* src = (r < 64) ? (oi_raw + r * D) : (oc_raw + (r - 64) * D);
  float v = src[t];
  __shared__ float red[128];
  red[t] = v * v;
  __syncthreads();
  for (int s = 64; s > 0; s >>= 1) {
    if (t < s) red[t] += red[t + s];
    __syncthreads();
  }
  out[r * D + t] = v / sqrtf(red[0]);
}

// ---------------- launch ----------------

extern "C" void kernel_launch(void* const* d_in, const int* in_sizes, int n_in,
                              void* d_out, int out_size, void* d_ws, size_t ws_size,
                              hipStream_t stream) {
  const float* images = (const float*)d_in[0];
  const int* node_types = (const int*)d_in[1];
  const int* erow = (const int*)d_in[2];
  const int* ecol = erow + NE;
  const float* eattr = (const float*)d_in[3];
  const int* batch = (const int*)d_in[4];
  const float* emb = (const float*)d_in[5];
  const float* W_img = (const float*)d_in[6];
  const float* b_img = (const float*)d_in[7];
  const float* W1 = (const float*)d_in[8];
  const float* b1 = (const float*)d_in[9];
  const float* W2 = (const float*)d_in[10];
  const float* b2 = (const float*)d_in[11];
  const float* W3 = (const float*)d_in[12];
  const float* b3 = (const float*)d_in[13];
  const float* Wi = (const float*)d_in[14];
  const float* bi = (const float*)d_in[15];
  const float* Wc = (const float*)d_in[16];
  const float* bc = (const float*)d_in[17];
  float* out = (float*)d_out;

  char* w = (char*)d_ws;
  auto alloc = [&](size_t bytes) -> void* {
    void* p = (void*)w;
    w += (bytes + 511) & ~(size_t)511;
    return p;
  };
  int* cnt8 = (int*)alloc((size_t)NB8 * 4);
  float* pooled = (float*)alloc(64 * D * 4);
  float* oi_raw = (float*)alloc(64 * D * 4);
  float* oc_raw = (float*)alloc(64 * D * 4);
  size_t zero_bytes = (size_t)(w - (char*)d_ws);  // cnt8+pooled+oi_raw+oc_raw zeroed
  int* csr_off = (int*)alloc((NN + 1) * 4);
  int* goff = (int*)alloc((NG + 1) * 4);
  int* scan_incl = (int*)alloc((size_t)NB8 * 4);
  int* scan_part = (int*)alloc(SCAN8_BLOCKS * 4);
  int* ex8 = (int*)alloc((size_t)NB8 * 4);
  int* slot = (int*)alloc((size_t)NE * 4);
  int2* edge_se = (int2*)alloc((size_t)NE * 8);
  int* src_s = (int*)alloc((size_t)NE * 4);
  float* norm_s = (float*)alloc((size_t)NE * 4);
  int* styp_s = (int*)alloc((size_t)NE * 4);
  float* dis = (float*)alloc(NN * 4);
  float* embW1 = (float*)alloc(NT * D * 4);
  uint* wbf2 = (uint*)alloc(D * 64 * 4);
  uint* wbf3 = (uint*)alloc(D * 64 * 4);
  uint* bufX = (uint*)alloc((size_t)NN * D * 2);      // X bf16 rows
  uint* bufB = (uint*)alloc((size_t)NN * D * 2);      // xw bf16 rows
  float* xi = (float*)alloc((size_t)64 * IMG * 4);
  float* xcat = (float*)alloc((size_t)64 * (IMG + D) * 4);
  uint* imgAbf = (uint*)alloc((size_t)64 * IMG * 2);
  float* splitbuf = (float*)alloc((size_t)8 * 64 * IMG * 4);

  hipMemsetAsync(d_ws, 0, zero_bytes, stream);

  // graph preprocessing (8-way sub-bucketed histogram)
  edge_slot<<<NE / 256, 256, 0, stream>>>(ecol, cnt8, slot);
  scan_blocks<<<SCAN8_BLOCKS, 256, 0, stream>>>(cnt8, scan_incl, scan_part);
  scan_partials<<<1, 256, 0, stream>>>(scan_part, SCAN8_BLOCKS);
  scan_apply8<<<SCAN8_BLOCKS, 256, 0, stream>>>(scan_incl, cnt8, scan_part, ex8, csr_off);
  fill_scatter<<<NE / 256, 256, 0, stream>>>(erow, ecol, eattr, ex8, slot, edge_se);
  deg_csr<<<(NN + 15) / 16, 256, 0, stream>>>(csr_off, edge_se, dis);
  norm_fill<<<(NN + 15) / 16, 256, 0, stream>>>(csr_off, edge_se, dis, node_types,
                                                src_s, norm_s, styp_s);

  // layer 1 collapsed + weight prep
  prep_weights<<<(NT * D + 2 * D * 64 + 255) / 256, 256, 0, stream>>>(
      emb, W1, embW1, W2, W3, wbf2, wbf3);
  lay1_fused<<<(NN + 15) / 16, 256, 0, stream>>>(csr_off, styp_s, norm_s, dis, node_types,
                                                 embW1, b1, bufX);

  // layers 2 & 3: MFMA GEMM + 2-node/wave aggregation; layer-3 output bf16 for pooling
  int gblk = (NN + 63) / 64;
  int ablk = (NN + 7) / 8;
  node_gemm_mfma<<<gblk, 256, 0, stream>>>(bufX, wbf2, bufB);
  aggregate2<<<ablk, 256, 0, stream>>>(bufB, csr_off, src_s, norm_s, dis, b2, 1,
                                       bufX, (float*)0);
  node_gemm_mfma<<<gblk, 256, 0, stream>>>(bufX, wbf3, bufB);
  aggregate2<<<ablk, 256, 0, stream>>>(bufB, csr_off, src_s, norm_s, dis, b3, 0,
                                       bufX, (float*)0);  // bf16 X3 -> bufX

  // pooling (bf16 input)
  graph_bounds<<<1, 128, 0, stream>>>(batch, goff);
  {
    dim3 g(NG, 8);
    pool_partial_bf<<<g, 64, 0, stream>>>(bufX, goff, pooled);
  }

  // image path: xi = images @ W_img.T + b_img  (bf16 MFMA, split-k)
  convA<<<(64 * IMG / 2 + 255) / 256, 256, 0, stream>>>(images, imgAbf);
  {
    dim3 g(IMG / 64, 8);
    img_mfma<<<g, 256, 0, stream>>>(imgAbf, W_img, splitbuf);
  }
  img_reduce<<<(64 * IMG + 255) / 256, 256, 0, stream>>>(splitbuf, b_img, xi);

  // oi = normalize(xi @ Wi.T + bi)   (bias folded into gemm64 y==0 block)
  {
    dim3 g(D / 64, 32);
    gemm64<<<g, 256, 0, stream>>>(xi, Wi, bi, oi_raw, D, IMG, 128);
  }
  // oc = normalize(concat(xi, pooled/cnt) @ Wc.T + bc)
  build_xcat<<<(64 * 1056 + 255) / 256, 256, 0, stream>>>(xi, pooled, goff, xcat);
  {
    dim3 g(D / 64, 24);
    gemm64<<<g, 256, 0, stream>>>(xcat, Wc, bc, oc_raw, D, IMG + D, 176);
  }
  normalize_rows<<<128, 128, 0, stream>>>(oi_raw, oc_raw, out);
}